// Round 7
// baseline (565.910 us; speedup 1.0000x reference)
//
#include <hip/hip_runtime.h>
#include <hip/hip_bf16.h>
#include <stdint.h>

#define NR 8192
#define FD 512
#define BM 64     // k_attn rows per band
#define BKC 128   // k_attn j per chunk

typedef __attribute__((ext_vector_type(8))) short s8v;   // 8 bf16 (4 VGPRs) - MFMA A/B frag
typedef __attribute__((ext_vector_type(4))) float f32x4; // MFMA C/D frag

static __device__ __forceinline__ short bf16_rtne(float x) {
    union { float f; uint32_t u; } v; v.f = x;
    uint32_t r = (v.u + 0x7FFFu + ((v.u >> 16) & 1u)) >> 16;
    return (short)r;
}
static __device__ __forceinline__ float bf16_to_f32(short s) {
    union { uint32_t u; float f; } v; v.u = ((uint32_t)(uint16_t)s) << 16;
    return v.f;
}

// ---------------- K0: adj -> bitmask (row-major u32 words) ----------------
// thread t: reads adj[t*32..+31], writes bm[t]. Pure HBM stream, no barriers.
__global__ void k_prepack(const int* __restrict__ adj, uint32_t* __restrict__ bm) {
    int t = blockIdx.x * 256 + threadIdx.x;          // 2,097,152 threads
    const int4* p = (const int4*)(adj + (size_t)t * 32);
    uint32_t word = 0;
#pragma unroll
    for (int g = 0; g < 8; ++g) {
        int4 v = p[g];
        word |= (uint32_t)(v.x != 0) << (g * 4);
        word |= (uint32_t)(v.y != 0) << (g * 4 + 1);
        word |= (uint32_t)(v.z != 0) << (g * 4 + 2);
        word |= (uint32_t)(v.w != 0) << (g * 4 + 3);
    }
    bm[t] = word;
}

// ---------------- K0a: fp32 -> bf16 convert (inp) ----------------
__global__ void k_convert(const float* __restrict__ in, short* __restrict__ out) {
    int i = blockIdx.x * blockDim.x + threadIdx.x;   // one float4 per thread
    float4 v = ((const float4*)in)[i];
    short4 s;
    s.x = bf16_rtne(v.x); s.y = bf16_rtne(v.y);
    s.z = bf16_rtne(v.z); s.w = bf16_rtne(v.w);
    ((short4*)out)[i] = s;
}

// ---------------- K0b: W1 [k][n] -> W1T bf16 [n][k] ----------------
__global__ void k_w1t(const float* __restrict__ W1, short* __restrict__ W1T) {
    int i = blockIdx.x * 256 + threadIdx.x;  // 512*512
    int k = i & 511, n = i >> 9;
    W1T[(size_t)n * 512 + k] = bf16_rtne(W1[(size_t)k * 512 + n]);
}

// ---------------- K1: h = inp @ W1 + b1 ; writes h AND ht2 ----------------
// ht2 layout: [jt=row/32][col][row%32] bf16 (tile-contiguous for k_attn B-frags)
__launch_bounds__(256)
__global__ void k_gemm_h(const short* __restrict__ A,   // inp bf16 [8192][512]
                         const short* __restrict__ BT,  // W1T bf16 [512][512]
                         const float* __restrict__ b1,
                         short* __restrict__ H,         // bf16 [8192][512]
                         short* __restrict__ HT2)       // bf16 [256][512][32]
{
    const int lane = threadIdx.x & 63;
    const int wn   = threadIdx.x >> 6;     // 0..3
    const int m    = lane & 15;
    const int q    = lane >> 4;
    const int r0   = blockIdx.x * 32;
    const int c0   = blockIdx.y * 128 + wn * 32;

    f32x4 acc[2][2] = {};
#pragma unroll 1
    for (int k0 = 0; k0 < 512; k0 += 32) {
        s8v a[2], b[2];
#pragma unroll
        for (int rt = 0; rt < 2; ++rt)
            a[rt] = *(const s8v*)(A + (size_t)(r0 + rt * 16 + m) * 512 + k0 + q * 8);
#pragma unroll
        for (int nt = 0; nt < 2; ++nt)
            b[nt] = *(const s8v*)(BT + (size_t)(c0 + nt * 16 + m) * 512 + k0 + q * 8);
#pragma unroll
        for (int rt = 0; rt < 2; ++rt)
#pragma unroll
            for (int nt = 0; nt < 2; ++nt)
                acc[rt][nt] = __builtin_amdgcn_mfma_f32_16x16x32_bf16(a[rt], b[nt], acc[rt][nt], 0, 0, 0);
    }
    float b1v[2];
#pragma unroll
    for (int nt = 0; nt < 2; ++nt) b1v[nt] = b1[c0 + nt * 16 + m];

#pragma unroll
    for (int rt = 0; rt < 2; ++rt)
#pragma unroll
        for (int nt = 0; nt < 2; ++nt) {
            int col = c0 + nt * 16 + m;
            short4 hp;
#pragma unroll
            for (int r = 0; r < 4; ++r) {
                int row = r0 + rt * 16 + q * 4 + r;
                short hv = bf16_rtne(acc[rt][nt][r] + b1v[nt]);
                H[(size_t)row * 512 + col] = hv;
                ((short*)&hp)[r] = hv;
            }
            *(short4*)(HT2 + (size_t)blockIdx.x * (512 * 32) + (size_t)col * 32 + rt * 16 + q * 4) = hp;
        }
}

// ---------------- K3: f1 = h@a1, f2s = h@a2 + b2 ----------------
__global__ void k_f1f2(const short* __restrict__ H, const float* __restrict__ a1,
                       const float* __restrict__ a2, const float* __restrict__ b2,
                       float* __restrict__ f1, float* __restrict__ f2s)
{
    const int lane = threadIdx.x & 63;
    const int row  = blockIdx.x * 4 + (threadIdx.x >> 6);
    s8v hv = *(const s8v*)(H + (size_t)row * 512 + lane * 8);
    float4 a1l = ((const float4*)(a1 + lane * 8))[0];
    float4 a1h = ((const float4*)(a1 + lane * 8))[1];
    float4 a2l = ((const float4*)(a2 + lane * 8))[0];
    float4 a2h = ((const float4*)(a2 + lane * 8))[1];
    float hf[8];
#pragma unroll
    for (int i = 0; i < 8; ++i) hf[i] = bf16_to_f32(hv[i]);
    float s1 = hf[0] * a1l.x + hf[1] * a1l.y + hf[2] * a1l.z + hf[3] * a1l.w
             + hf[4] * a1h.x + hf[5] * a1h.y + hf[6] * a1h.z + hf[7] * a1h.w;
    float s2 = hf[0] * a2l.x + hf[1] * a2l.y + hf[2] * a2l.z + hf[3] * a2l.w
             + hf[4] * a2h.x + hf[5] * a2h.y + hf[6] * a2h.z + hf[7] * a2h.w;
#pragma unroll
    for (int o = 32; o > 0; o >>= 1) {
        s1 += __shfl_xor(s1, o);
        s2 += __shfl_xor(s2, o);
    }
    if (lane == 0) {
        f1[row]  = s1;
        f2s[row] = s2 + b2[0];
    }
}

// ---------------- K4: fused masked-softmax attention @ h (partials) --------
// grid 512 = 128 bands x 4 j-splits -> 2 blocks/CU resident (16 waves/CU).
// Weight mask comes from the 8 MB bitmask (u16 per thread per chunk), so the
// per-chunk vmcnt drain at the barrier is ~100 B L1/L2 traffic, not a 64 KB
// HBM burst (rounds 5/6's serializer). 512 thr / 8 waves; wave tile 64r x 64c.
__launch_bounds__(512, 4)
__global__ void k_attn(const uint32_t* __restrict__ bm, // [8192][256] bit j
                       const short* __restrict__ HT2,   // [256][512][32]
                       const float* __restrict__ f1,
                       const float* __restrict__ f2s,
                       float* __restrict__ nump,        // [4][8192][512]
                       float* __restrict__ denomp)      // [4][8192]
{
    __shared__ __align__(16) short wt[2][BM * BKC];    // 32 KB

    const int t    = threadIdx.x;
    const int lane = t & 63;
    const int w    = t >> 6;          // 0..7 col group (64 cols)
    const int m    = lane & 15;
    const int q    = lane >> 4;

    const int js   = blockIdx.x & 3;
    const int band = blockIdx.x >> 2; // 0..127
    const int r0   = band * BM;
    const int jb0  = js * 2048;

    // producer: 1 row x 16 j per thread (64 rows x 8 groups)
    const int prow = t >> 3;          // 0..63
    const int jg   = t & 7;           // 16-j group within 128-chunk

    const float f1v = f1[r0 + prow];
    // u16 granule: bits [h*16, h*16+16) of row = mask for j in [h*16, +16)
    const uint16_t* bmp = (const uint16_t*)(bm + (size_t)(r0 + prow) * 256) + (jb0 >> 4) + jg;
    const float*    f2p = f2s + jb0 + jg * 16;

    f32x4 acc[4][4] = {};
    float dsum = 0.f;

    // prologue: prefetch chunk 0 (mask u16 + 16 f2 floats)
    uint32_t bits = bmp[0];
    float4 fv[4];
#pragma unroll
    for (int g = 0; g < 4; ++g) fv[g] = ((const float4*)f2p)[g];

#pragma unroll 1
    for (int ch = 0; ch < 2048 / BKC; ++ch) {
        const int p = ch & 1;
        // ---- phase 1: 16 weights from prefetched regs ----
        float wgt[16];
#pragma unroll
        for (int jj = 0; jj < 16; ++jj) {
            float s  = f1v + ((const float*)fv)[jj];
            float l  = fmaxf(s, 0.2f * s);
            float e  = __expf(l);
            float wv = ((bits >> jj) & 1u) ? e : 0.f;
            dsum += wv;
            wgt[jj] = wv;
        }
        s8v wv0, wv1;
#pragma unroll
        for (int jj = 0; jj < 8; ++jj) {
            wv0[jj] = bf16_rtne(wgt[jj]);
            wv1[jj] = bf16_rtne(wgt[8 + jj]);
        }
        const int sw = prow & 15;
        *(s8v*)&wt[p][prow * BKC + (((2 * jg) ^ sw) << 3)]     = wv0;
        *(s8v*)&wt[p][prow * BKC + (((2 * jg + 1) ^ sw) << 3)] = wv1;

        __syncthreads();

        // ---- prefetch next chunk (tiny: 2 B + 64 B, mostly L1) ----
        const int chn = (ch + 1) & (2048 / BKC - 1);   // wraps on last (dummy)
        bits = bmp[chn * 8];
#pragma unroll
        for (int g = 0; g < 4; ++g) fv[g] = ((const float4*)(f2p + chn * BKC))[g];

        // ---- phase 2: 4 barrier-free k-steps ----
#pragma unroll
        for (int kk = 0; kk < 4; ++kk) {
            const int jt = (jb0 + ch * BKC + kk * 32) >> 5;
            const short* hb = HT2 + (size_t)jt * 16384 + q * 8;
            s8v af[4];
#pragma unroll
            for (int i = 0; i < 4; ++i) {
                int row = i * 16 + m;
                af[i] = *(const s8v*)&wt[p][row * BKC + (((kk * 4 + q) ^ m) << 3)];
            }
#pragma unroll
            for (int nt = 0; nt < 4; ++nt) {
                s8v b = *(const s8v*)(hb + (size_t)(w * 64 + nt * 16 + m) * 32);
#pragma unroll
                for (int i = 0; i < 4; ++i)
                    acc[i][nt] = __builtin_amdgcn_mfma_f32_16x16x32_bf16(af[i], b, acc[i][nt], 0, 0, 0);
            }
        }
    }

    // ---- partial denominators: reduce over the 8 producer threads per row
    dsum += __shfl_xor(dsum, 1);
    dsum += __shfl_xor(dsum, 2);
    dsum += __shfl_xor(dsum, 4);
    if (jg == 0) denomp[(size_t)js * NR + r0 + prow] = dsum;

    // ---- partial numerators
    float* np = nump + (size_t)js * NR * FD;
#pragma unroll
    for (int i = 0; i < 4; ++i)
#pragma unroll
        for (int nt = 0; nt < 4; ++nt)
#pragma unroll
            for (int r = 0; r < 4; ++r) {
                int row = r0 + i * 16 + q * 4 + r;
                int col = w * 64 + nt * 16 + m;
                np[(size_t)row * FD + col] = acc[i][nt][r];
            }
}

// ---------------- K5: combine j-split partials, softmax divide, ELU --------
__global__ void k_combine(const float* __restrict__ nump,
                          const float* __restrict__ denomp,
                          float* __restrict__ out)
{
    size_t e = ((size_t)blockIdx.x * 256 + threadIdx.x) * 4;
    int row = (int)(e >> 9);
    float4 n0 = *(const float4*)(nump + e);
    float4 n1 = *(const float4*)(nump + (size_t)NR * FD + e);
    float4 n2 = *(const float4*)(nump + (size_t)2 * NR * FD + e);
    float4 n3 = *(const float4*)(nump + (size_t)3 * NR * FD + e);
    float d = denomp[row] + denomp[NR + row] + denomp[2 * NR + row] + denomp[3 * NR + row];
    float inv = 1.0f / d;
    float4 o;
    o.x = (n0.x + n1.x + n2.x + n3.x) * inv;
    o.y = (n0.y + n1.y + n2.y + n3.y) * inv;
    o.z = (n0.z + n1.z + n2.z + n3.z) * inv;
    o.w = (n0.w + n1.w + n2.w + n3.w) * inv;
    o.x = (o.x > 0.f) ? o.x : (__expf(o.x) - 1.f);
    o.y = (o.y > 0.f) ? o.y : (__expf(o.y) - 1.f);
    o.z = (o.z > 0.f) ? o.z : (__expf(o.z) - 1.f);
    o.w = (o.w > 0.f) ? o.w : (__expf(o.w) - 1.f);
    *(float4*)(out + e) = o;
}

extern "C" void kernel_launch(void* const* d_in, const int* in_sizes, int n_in,
                              void* d_out, int out_size, void* d_ws, size_t ws_size,
                              hipStream_t stream) {
    const float* inp = (const float*)d_in[0];
    const int*   adj = (const int*)d_in[1];
    const float* W1  = (const float*)d_in[2];
    const float* b1  = (const float*)d_in[3];
    const float* a1  = (const float*)d_in[4];
    const float* a2  = (const float*)d_in[5];
    const float* b2  = (const float*)d_in[6];
    float* out = (float*)d_out;

    // workspace layout
    short*    inp_bf = (short*)d_ws;                        // 8 MB
    short*    w1t    = inp_bf + (size_t)NR * FD;            // 0.5 MB
    short*    h      = w1t + (size_t)FD * FD;               // 8 MB
    short*    ht2    = h + (size_t)NR * FD;                 // 8 MB
    uint32_t* bmw    = (uint32_t*)(ht2 + (size_t)FD * NR);  // 8 MB
    float*    f1     = (float*)(bmw + (size_t)NR * 256);    // 32 KB
    float*    f2s    = f1 + NR;                             // 32 KB
    float*    nump   = f2s + NR;                            // 64 MB
    float*    denomp = nump + (size_t)4 * NR * FD;          // 128 KB

    k_prepack<<<NR * 256 / 256, 256, 0, stream>>>(adj, bmw);
    k_convert<<<(NR * FD / 4) / 256, 256, 0, stream>>>(inp, inp_bf);
    k_w1t<<<(FD * FD) / 256, 256, 0, stream>>>(W1, w1t);
    dim3 g1(NR / 32, FD / 128);
    k_gemm_h<<<g1, 256, 0, stream>>>(inp_bf, w1t, b1, h, ht2);
    k_f1f2<<<NR / 4, 256, 0, stream>>>(h, a1, a2, b2, f1, f2s);
    k_attn<<<128 * 4, 512, 0, stream>>>(bmw, ht2, f1, f2s, nump, denomp);
    k_combine<<<(NR * FD / 4) / 256, 256, 0, stream>>>(nump, denomp, out);
}

// Round 8
// 537.700 us; speedup vs baseline: 1.0525x; 1.0525x over previous
//
#include <hip/hip_runtime.h>
#include <hip/hip_bf16.h>
#include <stdint.h>

#define NR 8192
#define FD 512
#define BM 64     // k_attn rows per band
#define BKC 256   // k_attn j per chunk

typedef __attribute__((ext_vector_type(8))) short s8v;   // 8 bf16 (4 VGPRs) - MFMA A/B frag
typedef __attribute__((ext_vector_type(4))) float f32x4; // MFMA C/D frag

static __device__ __forceinline__ short bf16_rtne(float x) {
    union { float f; uint32_t u; } v; v.f = x;
    uint32_t r = (v.u + 0x7FFFu + ((v.u >> 16) & 1u)) >> 16;
    return (short)r;
}
static __device__ __forceinline__ float bf16_to_f32(short s) {
    union { uint32_t u; float f; } v; v.u = ((uint32_t)(uint16_t)s) << 16;
    return v.f;
}

// ---------------- K0: adj -> bitmask via ballot ----------------
// wave handles (row, 2048-j segment); lane L owns j0+L so __ballot packs 64
// consecutive j's into one u64 in j-order. Fully coalesced 256B wave-loads.
__global__ void k_prepack(const int* __restrict__ adj,
                          unsigned long long* __restrict__ bm) {
    const int lane = threadIdx.x & 63;
    const int wv   = threadIdx.x >> 6;          // 4 waves/block
    const int gid  = blockIdx.x * 4 + wv;       // 32768 waves
    const int row  = gid >> 2;
    const int seg  = (gid & 3) * 2048;
    const int* p   = adj + (size_t)row * NR + seg + lane;
    unsigned long long* o = bm + (((size_t)row * NR + seg) >> 6);
#pragma unroll
    for (int g = 0; g < 8; ++g) {               // 8 groups of 256 j
        unsigned long long b0 = __ballot(p[g * 256]       != 0);
        unsigned long long b1 = __ballot(p[g * 256 + 64]  != 0);
        unsigned long long b2 = __ballot(p[g * 256 + 128] != 0);
        unsigned long long b3 = __ballot(p[g * 256 + 192] != 0);
        unsigned long long vs = (lane == 0) ? b0 : (lane == 1) ? b1
                              : (lane == 2) ? b2 : b3;
        if (lane < 4) o[g * 4 + lane] = vs;
    }
}

// ---------------- K0a: fp32 -> bf16 convert (inp) ----------------
__global__ void k_convert(const float* __restrict__ in, short* __restrict__ out) {
    int i = blockIdx.x * blockDim.x + threadIdx.x;   // one float4 per thread
    float4 v = ((const float4*)in)[i];
    short4 s;
    s.x = bf16_rtne(v.x); s.y = bf16_rtne(v.y);
    s.z = bf16_rtne(v.z); s.w = bf16_rtne(v.w);
    ((short4*)out)[i] = s;
}

// ---------------- K0b: W1 [k][n] -> W1T bf16 [n][k] ----------------
__global__ void k_w1t(const float* __restrict__ W1, short* __restrict__ W1T) {
    int i = blockIdx.x * 256 + threadIdx.x;  // 512*512
    int k = i & 511, n = i >> 9;
    W1T[(size_t)n * 512 + k] = bf16_rtne(W1[(size_t)k * 512 + n]);
}

// ---------------- K1: h = inp @ W1 + b1 ; writes h AND ht2 ----------------
// ht2 layout: [jt=row/32][col][row%32] bf16 (tile-contiguous for k_attn B-frags)
__launch_bounds__(256)
__global__ void k_gemm_h(const short* __restrict__ A,   // inp bf16 [8192][512]
                         const short* __restrict__ BT,  // W1T bf16 [512][512]
                         const float* __restrict__ b1,
                         short* __restrict__ H,         // bf16 [8192][512]
                         short* __restrict__ HT2)       // bf16 [256][512][32]
{
    const int lane = threadIdx.x & 63;
    const int wn   = threadIdx.x >> 6;     // 0..3
    const int m    = lane & 15;
    const int q    = lane >> 4;
    const int r0   = blockIdx.x * 32;
    const int c0   = blockIdx.y * 128 + wn * 32;

    f32x4 acc[2][2] = {};
#pragma unroll 1
    for (int k0 = 0; k0 < 512; k0 += 32) {
        s8v a[2], b[2];
#pragma unroll
        for (int rt = 0; rt < 2; ++rt)
            a[rt] = *(const s8v*)(A + (size_t)(r0 + rt * 16 + m) * 512 + k0 + q * 8);
#pragma unroll
        for (int nt = 0; nt < 2; ++nt)
            b[nt] = *(const s8v*)(BT + (size_t)(c0 + nt * 16 + m) * 512 + k0 + q * 8);
#pragma unroll
        for (int rt = 0; rt < 2; ++rt)
#pragma unroll
            for (int nt = 0; nt < 2; ++nt)
                acc[rt][nt] = __builtin_amdgcn_mfma_f32_16x16x32_bf16(a[rt], b[nt], acc[rt][nt], 0, 0, 0);
    }
    float b1v[2];
#pragma unroll
    for (int nt = 0; nt < 2; ++nt) b1v[nt] = b1[c0 + nt * 16 + m];

#pragma unroll
    for (int rt = 0; rt < 2; ++rt)
#pragma unroll
        for (int nt = 0; nt < 2; ++nt) {
            int col = c0 + nt * 16 + m;
            short4 hp;
#pragma unroll
            for (int r = 0; r < 4; ++r) {
                int row = r0 + rt * 16 + q * 4 + r;
                short hv = bf16_rtne(acc[rt][nt][r] + b1v[nt]);
                H[(size_t)row * 512 + col] = hv;
                ((short*)&hp)[r] = hv;
            }
            *(short4*)(HT2 + (size_t)blockIdx.x * (512 * 32) + (size_t)col * 32 + rt * 16 + q * 4) = hp;
        }
}

// ---------------- K3: f1 = h@a1, f2s = h@a2 + b2 ----------------
__global__ void k_f1f2(const short* __restrict__ H, const float* __restrict__ a1,
                       const float* __restrict__ a2, const float* __restrict__ b2,
                       float* __restrict__ f1, float* __restrict__ f2s)
{
    const int lane = threadIdx.x & 63;
    const int row  = blockIdx.x * 4 + (threadIdx.x >> 6);
    s8v hv = *(const s8v*)(H + (size_t)row * 512 + lane * 8);
    float4 a1l = ((const float4*)(a1 + lane * 8))[0];
    float4 a1h = ((const float4*)(a1 + lane * 8))[1];
    float4 a2l = ((const float4*)(a2 + lane * 8))[0];
    float4 a2h = ((const float4*)(a2 + lane * 8))[1];
    float hf[8];
#pragma unroll
    for (int i = 0; i < 8; ++i) hf[i] = bf16_to_f32(hv[i]);
    float s1 = hf[0] * a1l.x + hf[1] * a1l.y + hf[2] * a1l.z + hf[3] * a1l.w
             + hf[4] * a1h.x + hf[5] * a1h.y + hf[6] * a1h.z + hf[7] * a1h.w;
    float s2 = hf[0] * a2l.x + hf[1] * a2l.y + hf[2] * a2l.z + hf[3] * a2l.w
             + hf[4] * a2h.x + hf[5] * a2h.y + hf[6] * a2h.z + hf[7] * a2h.w;
#pragma unroll
    for (int o = 32; o > 0; o >>= 1) {
        s1 += __shfl_xor(s1, o);
        s2 += __shfl_xor(s2, o);
    }
    if (lane == 0) {
        f1[row]  = s1;
        f2s[row] = s2 + b2[0];
    }
}

// ---------------- K4: fused masked-softmax attention @ h (partials) --------
// grid 512 = 128 bands x 4 j-splits, 1024 thr = 16 waves (1 block/CU, 50% occ).
// Wave w = col group (32 cols), all 64 rows (af[4], acc[4][2]=32 VGPR).
// Software-pipelined: per chunk one barrier; phase2(ch) MFMAs and
// phase1(ch+1) weight-VALU live in the same barrier-free region so the
// MFMA and VALU pipes co-schedule (m114) and load latency hides under MFMAs.
__launch_bounds__(1024, 4)
__global__ void k_attn(const uint32_t* __restrict__ bm, // [8192][256] bit j
                       const short* __restrict__ HT2,   // [256][512][32]
                       const float* __restrict__ f1,
                       const float* __restrict__ f2s,
                       float* __restrict__ nump,        // [4][8192][512]
                       float* __restrict__ denomp)      // [4][8192]
{
    __shared__ __align__(16) short wt[2][BM * BKC];    // 2 x 32 KB

    const int t    = threadIdx.x;
    const int lane = t & 63;
    const int w    = t >> 6;          // 0..15 col group (32 cols)
    const int m    = lane & 15;
    const int q    = lane >> 4;

    const int js   = blockIdx.x & 3;
    const int band = blockIdx.x >> 2; // 0..127
    const int r0   = band * BM;
    const int jb0  = js * 2048;

    // producer: 1 row x 16 j per thread (64 rows x 16 groups)
    const int prow = t >> 4;          // 0..63
    const int jg   = t & 15;          // 16-j group within 256-chunk

    const float f1v = f1[r0 + prow];
    const uint16_t* bmp = (const uint16_t*)bm + (((size_t)(r0 + prow) * NR + jb0) >> 4) + jg;
    const float*    f2p = f2s + jb0 + jg * 16;

    f32x4 acc[4][2] = {};
    float dsum = 0.f;

    uint32_t bits;
    float4 fv[4];

#define GAT_PHASE1(PN)                                                        \
    {                                                                         \
        s8v wv0, wv1;                                                         \
        _Pragma("unroll")                                                     \
        for (int jj = 0; jj < 8; ++jj) {                                      \
            float s_ = f1v + ((const float*)fv)[jj];                          \
            float e_ = __expf(fmaxf(s_, 0.2f * s_));                          \
            float x_ = ((bits >> jj) & 1u) ? e_ : 0.f;                        \
            dsum += x_;                                                       \
            wv0[jj] = bf16_rtne(x_);                                          \
        }                                                                     \
        _Pragma("unroll")                                                     \
        for (int jj = 0; jj < 8; ++jj) {                                      \
            float s_ = f1v + ((const float*)fv)[8 + jj];                      \
            float e_ = __expf(fmaxf(s_, 0.2f * s_));                          \
            float x_ = ((bits >> (8 + jj)) & 1u) ? e_ : 0.f;                  \
            dsum += x_;                                                       \
            wv1[jj] = bf16_rtne(x_);                                          \
        }                                                                     \
        const int sw = prow & 15;                                             \
        *(s8v*)&wt[PN][prow * BKC + (((2 * jg) ^ sw) << 3)]     = wv0;        \
        *(s8v*)&wt[PN][prow * BKC + (((2 * jg + 1) ^ sw) << 3)] = wv1;        \
    }

    // prologue: load + phase1 for chunk 0
    bits = bmp[0];
#pragma unroll
    for (int g = 0; g < 4; ++g) fv[g] = ((const float4*)f2p)[g];
    GAT_PHASE1(0)
    __syncthreads();

#pragma unroll 1
    for (int ch = 0; ch < 2048 / BKC; ++ch) {
        const int p   = ch & 1;
        const int chn = ch + 1;
        const bool more = (chn < 2048 / BKC);
        // loads for next chunk (L1/L2-resident; overlap MFMAs below)
        if (more) {
            bits = bmp[chn * 16];
#pragma unroll
            for (int g = 0; g < 4; ++g) fv[g] = ((const float4*)(f2p + chn * BKC))[g];
        }

        // ---- phase 2: 8 barrier-free k-steps on wt[p] ----
#pragma unroll
        for (int kk = 0; kk < 8; ++kk) {
            const int jt = (jb0 + ch * BKC + kk * 32) >> 5;
            const short* hb = HT2 + (size_t)jt * 16384 + q * 8;
            s8v b0 = *(const s8v*)(hb + (size_t)(w * 32 + m) * 32);
            s8v b1 = *(const s8v*)(hb + (size_t)(w * 32 + 16 + m) * 32);
            s8v af[4];
#pragma unroll
            for (int i = 0; i < 4; ++i)
                af[i] = *(const s8v*)&wt[p][(i * 16 + m) * BKC + (((kk * 4 + q) ^ m) << 3)];
#pragma unroll
            for (int i = 0; i < 4; ++i) {
                acc[i][0] = __builtin_amdgcn_mfma_f32_16x16x32_bf16(af[i], b0, acc[i][0], 0, 0, 0);
                acc[i][1] = __builtin_amdgcn_mfma_f32_16x16x32_bf16(af[i], b1, acc[i][1], 0, 0, 0);
            }
        }

        // ---- phase 1 for next chunk into wt[p^1] (co-scheduled with MFMAs)
        if (more) GAT_PHASE1(p ^ 1)

        __syncthreads();
    }
#undef GAT_PHASE1

    // ---- partial denominators: reduce over the 16 producer threads per row
    dsum += __shfl_xor(dsum, 1);
    dsum += __shfl_xor(dsum, 2);
    dsum += __shfl_xor(dsum, 4);
    dsum += __shfl_xor(dsum, 8);
    if (jg == 0) denomp[(size_t)js * NR + r0 + prow] = dsum;

    // ---- partial numerators
    float* np = nump + (size_t)js * NR * FD;
#pragma unroll
    for (int i = 0; i < 4; ++i)
#pragma unroll
        for (int nt = 0; nt < 2; ++nt)
#pragma unroll
            for (int r = 0; r < 4; ++r) {
                int row = r0 + i * 16 + q * 4 + r;
                int col = w * 32 + nt * 16 + m;
                np[(size_t)row * FD + col] = acc[i][nt][r];
            }
}

// ---------------- K5: combine j-split partials, softmax divide, ELU --------
__global__ void k_combine(const float* __restrict__ nump,
                          const float* __restrict__ denomp,
                          float* __restrict__ out)
{
    size_t e = ((size_t)blockIdx.x * 256 + threadIdx.x) * 4;
    int row = (int)(e >> 9);
    float4 n0 = *(const float4*)(nump + e);
    float4 n1 = *(const float4*)(nump + (size_t)NR * FD + e);
    float4 n2 = *(const float4*)(nump + (size_t)2 * NR * FD + e);
    float4 n3 = *(const float4*)(nump + (size_t)3 * NR * FD + e);
    float d = denomp[row] + denomp[NR + row] + denomp[2 * NR + row] + denomp[3 * NR + row];
    float inv = 1.0f / d;
    float4 o;
    o.x = (n0.x + n1.x + n2.x + n3.x) * inv;
    o.y = (n0.y + n1.y + n2.y + n3.y) * inv;
    o.z = (n0.z + n1.z + n2.z + n3.z) * inv;
    o.w = (n0.w + n1.w + n2.w + n3.w) * inv;
    o.x = (o.x > 0.f) ? o.x : (__expf(o.x) - 1.f);
    o.y = (o.y > 0.f) ? o.y : (__expf(o.y) - 1.f);
    o.z = (o.z > 0.f) ? o.z : (__expf(o.z) - 1.f);
    o.w = (o.w > 0.f) ? o.w : (__expf(o.w) - 1.f);
    *(float4*)(out + e) = o;
}

extern "C" void kernel_launch(void* const* d_in, const int* in_sizes, int n_in,
                              void* d_out, int out_size, void* d_ws, size_t ws_size,
                              hipStream_t stream) {
    const float* inp = (const float*)d_in[0];
    const int*   adj = (const int*)d_in[1];
    const float* W1  = (const float*)d_in[2];
    const float* b1  = (const float*)d_in[3];
    const float* a1  = (const float*)d_in[4];
    const float* a2  = (const float*)d_in[5];
    const float* b2  = (const float*)d_in[6];
    float* out = (float*)d_out;

    // workspace layout
    short*    inp_bf = (short*)d_ws;                        // 8 MB
    short*    w1t    = inp_bf + (size_t)NR * FD;            // 0.5 MB
    short*    h      = w1t + (size_t)FD * FD;               // 8 MB
    short*    ht2    = h + (size_t)NR * FD;                 // 8 MB
    uint32_t* bmw    = (uint32_t*)(ht2 + (size_t)FD * NR);  // 8 MB
    float*    f1     = (float*)(bmw + (size_t)NR * 256);    // 32 KB
    float*    f2s    = f1 + NR;                             // 32 KB
    float*    nump   = f2s + NR;                            // 64 MB
    float*    denomp = nump + (size_t)4 * NR * FD;          // 128 KB

    k_prepack<<<NR, 256, 0, stream>>>(adj, (unsigned long long*)bmw);
    k_convert<<<(NR * FD / 4) / 256, 256, 0, stream>>>(inp, inp_bf);
    k_w1t<<<(FD * FD) / 256, 256, 0, stream>>>(W1, w1t);
    dim3 g1(NR / 32, FD / 128);
    k_gemm_h<<<g1, 256, 0, stream>>>(inp_bf, w1t, b1, h, ht2);
    k_f1f2<<<NR / 4, 256, 0, stream>>>(h, a1, a2, b2, f1, f2s);
    k_attn<<<128 * 4, 1024, 0, stream>>>(bmw, ht2, f1, f2s, nump, denomp);
    k_combine<<<(NR * FD / 4) / 256, 256, 0, stream>>>(nump, denomp, out);
}

// Round 9
// 525.842 us; speedup vs baseline: 1.0762x; 1.0226x over previous
//
#include <hip/hip_runtime.h>
#include <hip/hip_bf16.h>
#include <stdint.h>

#define NR 8192
#define FD 512
#define BM 64     // k_attn rows per band
#define PADC 36   // padded shorts per col per 32-j tile (32 + 4 pad)

typedef __attribute__((ext_vector_type(8))) short s8v;   // 8 bf16 (4 VGPRs) - MFMA A/B frag
typedef __attribute__((ext_vector_type(4))) float f32x4; // MFMA C/D frag

static __device__ __forceinline__ short bf16_rtne(float x) {
    union { float f; uint32_t u; } v; v.f = x;
    uint32_t r = (v.u + 0x7FFFu + ((v.u >> 16) & 1u)) >> 16;
    return (short)r;
}
static __device__ __forceinline__ float bf16_to_f32(short s) {
    union { uint32_t u; float f; } v; v.u = ((uint32_t)(uint16_t)s) << 16;
    return v.f;
}

// ---------------- K0: adj -> bitmask via ballot ----------------
__global__ void k_prepack(const int* __restrict__ adj,
                          unsigned long long* __restrict__ bm) {
    const int lane = threadIdx.x & 63;
    const int wv   = threadIdx.x >> 6;          // 4 waves/block
    const int gid  = blockIdx.x * 4 + wv;       // 32768 waves
    const int row  = gid >> 2;
    const int seg  = (gid & 3) * 2048;
    const int* p   = adj + (size_t)row * NR + seg + lane;
    unsigned long long* o = bm + (((size_t)row * NR + seg) >> 6);
#pragma unroll
    for (int g = 0; g < 8; ++g) {               // 8 groups of 256 j
        unsigned long long b0 = __ballot(p[g * 256]       != 0);
        unsigned long long b1 = __ballot(p[g * 256 + 64]  != 0);
        unsigned long long b2 = __ballot(p[g * 256 + 128] != 0);
        unsigned long long b3 = __ballot(p[g * 256 + 192] != 0);
        unsigned long long vs = (lane == 0) ? b0 : (lane == 1) ? b1
                              : (lane == 2) ? b2 : b3;
        if (lane < 4) o[g * 4 + lane] = vs;
    }
}

// ---------------- K0a: fp32 -> bf16 convert (inp) ----------------
__global__ void k_convert(const float* __restrict__ in, short* __restrict__ out) {
    int i = blockIdx.x * blockDim.x + threadIdx.x;   // one float4 per thread
    float4 v = ((const float4*)in)[i];
    short4 s;
    s.x = bf16_rtne(v.x); s.y = bf16_rtne(v.y);
    s.z = bf16_rtne(v.z); s.w = bf16_rtne(v.w);
    ((short4*)out)[i] = s;
}

// ---------------- K0b: W1 [k][n] -> W1T bf16 [n][k] ----------------
__global__ void k_w1t(const float* __restrict__ W1, short* __restrict__ W1T) {
    int i = blockIdx.x * 256 + threadIdx.x;  // 512*512
    int k = i & 511, n = i >> 9;
    W1T[(size_t)n * 512 + k] = bf16_rtne(W1[(size_t)k * 512 + n]);
}

// ---------------- K1: h = inp @ W1 + b1 ; writes h AND ht36 ----------------
// ht36 layout: [jt=row/32][col][PADC] bf16 tiles (36 KB, DMA-linear for k_attn;
// the 4-short pad makes LDS reads bank-conflict-free and 8B-aligned)
__launch_bounds__(256)
__global__ void k_gemm_h(const short* __restrict__ A,   // inp bf16 [8192][512]
                         const short* __restrict__ BT,  // W1T bf16 [512][512]
                         const float* __restrict__ b1,
                         short* __restrict__ H,         // bf16 [8192][512]
                         short* __restrict__ HT36)      // bf16 [256][512][36]
{
    const int lane = threadIdx.x & 63;
    const int wn   = threadIdx.x >> 6;     // 0..3
    const int m    = lane & 15;
    const int q    = lane >> 4;
    const int r0   = blockIdx.x * 32;
    const int c0   = blockIdx.y * 128 + wn * 32;

    f32x4 acc[2][2] = {};
#pragma unroll 1
    for (int k0 = 0; k0 < 512; k0 += 32) {
        s8v a[2], b[2];
#pragma unroll
        for (int rt = 0; rt < 2; ++rt)
            a[rt] = *(const s8v*)(A + (size_t)(r0 + rt * 16 + m) * 512 + k0 + q * 8);
#pragma unroll
        for (int nt = 0; nt < 2; ++nt)
            b[nt] = *(const s8v*)(BT + (size_t)(c0 + nt * 16 + m) * 512 + k0 + q * 8);
#pragma unroll
        for (int rt = 0; rt < 2; ++rt)
#pragma unroll
            for (int nt = 0; nt < 2; ++nt)
                acc[rt][nt] = __builtin_amdgcn_mfma_f32_16x16x32_bf16(a[rt], b[nt], acc[rt][nt], 0, 0, 0);
    }
    float b1v[2];
#pragma unroll
    for (int nt = 0; nt < 2; ++nt) b1v[nt] = b1[c0 + nt * 16 + m];

#pragma unroll
    for (int rt = 0; rt < 2; ++rt)
#pragma unroll
        for (int nt = 0; nt < 2; ++nt) {
            int col = c0 + nt * 16 + m;
            short4 hp;
#pragma unroll
            for (int r = 0; r < 4; ++r) {
                int row = r0 + rt * 16 + q * 4 + r;
                short hv = bf16_rtne(acc[rt][nt][r] + b1v[nt]);
                H[(size_t)row * 512 + col] = hv;
                ((short*)&hp)[r] = hv;
            }
            *(short4*)(HT36 + (size_t)blockIdx.x * (512 * PADC)
                             + (size_t)col * PADC + rt * 16 + q * 4) = hp;
        }
}

// ---------------- K3: f1 = h@a1, f2s = h@a2 + b2 ----------------
__global__ void k_f1f2(const short* __restrict__ H, const float* __restrict__ a1,
                       const float* __restrict__ a2, const float* __restrict__ b2,
                       float* __restrict__ f1, float* __restrict__ f2s)
{
    const int lane = threadIdx.x & 63;
    const int row  = blockIdx.x * 4 + (threadIdx.x >> 6);
    s8v hv = *(const s8v*)(H + (size_t)row * 512 + lane * 8);
    float4 a1l = ((const float4*)(a1 + lane * 8))[0];
    float4 a1h = ((const float4*)(a1 + lane * 8))[1];
    float4 a2l = ((const float4*)(a2 + lane * 8))[0];
    float4 a2h = ((const float4*)(a2 + lane * 8))[1];
    float hf[8];
#pragma unroll
    for (int i = 0; i < 8; ++i) hf[i] = bf16_to_f32(hv[i]);
    float s1 = hf[0] * a1l.x + hf[1] * a1l.y + hf[2] * a1l.z + hf[3] * a1l.w
             + hf[4] * a1h.x + hf[5] * a1h.y + hf[6] * a1h.z + hf[7] * a1h.w;
    float s2 = hf[0] * a2l.x + hf[1] * a2l.y + hf[2] * a2l.z + hf[3] * a2l.w
             + hf[4] * a2h.x + hf[5] * a2h.y + hf[6] * a2h.z + hf[7] * a2h.w;
#pragma unroll
    for (int o = 32; o > 0; o >>= 1) {
        s1 += __shfl_xor(s1, o);
        s2 += __shfl_xor(s2, o);
    }
    if (lane == 0) {
        f1[row]  = s1;
        f2s[row] = s2 + b2[0];
    }
}

// ---------------- K4: fused masked-softmax attention @ h (partials) --------
// grid 512 = 128 bands x 4 js, 512 thr / 8 waves, LDS 80 KB -> 2 blocks/CU.
// m97-style: per 32-j k-step, async-DMA the NEXT B-tile (36 KB, padded) into
// LDS dbuf (global_load_lds: no VGPR cost -> full latency hiding) + compute
// next step's 64x32 weight tile into wt dbuf; MFMA current step from LDS.
// One barrier/kk; vmcnt drain covers a DMA issued a whole step earlier.
__launch_bounds__(512, 4)
__global__ void k_attn(const uint32_t* __restrict__ bm, // [8192][256] bit j
                       const short* __restrict__ HT36,  // [256][512][36]
                       const float* __restrict__ f1,
                       const float* __restrict__ f2s,
                       float* __restrict__ nump,        // [4][8192][512]
                       float* __restrict__ denomp)      // [4][8192]
{
    __shared__ __align__(16) short bbuf[2][512 * PADC]; // 72 KB
    __shared__ __align__(16) short wt[2][BM * 32];      // 8 KB

    const int t    = threadIdx.x;
    const int lane = t & 63;
    const int w    = t >> 6;          // 0..7 col group (64 cols)
    const int m    = lane & 15;
    const int q    = lane >> 4;

    const int js   = blockIdx.x & 3;
    const int band = blockIdx.x >> 2; // 0..127
    const int r0   = band * BM;
    const int jb0  = js * 2048;

    // weight producer: 1 row x 4 j per k-step
    const int prow = t >> 3;          // 0..63
    const int jg   = t & 7;           // 4-j group within 32-j step

    const float f1v = f1[r0 + prow];
    const uint32_t* bmrow = bm + (size_t)(r0 + prow) * 256 + js * 64; // word per k-step
    const float*    f2p   = f2s + jb0 + jg * 4;

    f32x4 acc[4][4] = {};
    float dsum = 0.f;

#define GAT_DMA(KT, PN)                                                        \
    {                                                                          \
        const short* srcb = HT36 + (size_t)(js * 64 + (KT)) * (512 * PADC);    \
        short* dstb = &bbuf[PN][0];                                            \
        _Pragma("unroll")                                                      \
        for (int r_ = 0; r_ < 5; ++r_) {                                       \
            int g_ = w + 8 * r_;                                               \
            if (g_ < 36) {                                                     \
                __builtin_amdgcn_global_load_lds(                              \
                    (const __attribute__((address_space(1))) int*)             \
                        (srcb + g_ * 512 + lane * 8),                          \
                    (__attribute__((address_space(3))) int*)(dstb + g_ * 512), \
                    16, 0, 0);                                                 \
            }                                                                  \
        }                                                                      \
    }

#define GAT_WGEN(KT, PN)                                                       \
    {                                                                          \
        uint32_t wd_ = bmrow[KT];                                              \
        float4 f2_ = *(const float4*)(f2p + (KT) * 32);                        \
        uint32_t nib_ = wd_ >> (jg * 4);                                       \
        short4 sv_;                                                            \
        _Pragma("unroll")                                                      \
        for (int jj = 0; jj < 4; ++jj) {                                       \
            float s_ = f1v + ((const float*)&f2_)[jj];                         \
            float e_ = __expf(fmaxf(s_, 0.2f * s_));                           \
            float x_ = ((nib_ >> jj) & 1u) ? e_ : 0.f;                         \
            dsum += x_;                                                        \
            ((short*)&sv_)[jj] = bf16_rtne(x_);                                \
        }                                                                      \
        *(short4*)&wt[PN][prow * 32 + (((jg >> 1) ^ (prow & 3)) << 3)          \
                          + (jg & 1) * 4] = sv_;                               \
    }

    // prologue: stage k-step 0
    GAT_DMA(0, 0)
    GAT_WGEN(0, 0)
    __syncthreads();

#pragma unroll 1
    for (int kk = 0; kk < 64; ++kk) {
        const int p = kk & 1;
        const bool more = (kk < 63);

        // async-stage next B tile + next weights (no VGPR round-trip for B)
        if (more) GAT_DMA(kk + 1, p ^ 1)

        // MFMA current step from LDS
        s8v af[4];
#pragma unroll
        for (int i = 0; i < 4; ++i)
            af[i] = *(const s8v*)&wt[p][(i * 16 + m) * 32 + ((q ^ (m & 3)) << 3)];
        const short* bb = &bbuf[p][0];
#pragma unroll
        for (int nt = 0; nt < 4; ++nt) {
            int col = w * 64 + nt * 16 + m;
            union { short4 h[2]; s8v v; } bu;
            bu.h[0] = *(const short4*)&bb[col * PADC + q * 8];
            bu.h[1] = *(const short4*)&bb[col * PADC + q * 8 + 4];
#pragma unroll
            for (int i = 0; i < 4; ++i)
                acc[i][nt] = __builtin_amdgcn_mfma_f32_16x16x32_bf16(af[i], bu.v, acc[i][nt], 0, 0, 0);
        }

        // weights for next step (VALU overlaps MFMA shadow)
        if (more) GAT_WGEN(kk + 1, p ^ 1)

        __syncthreads();
    }
#undef GAT_DMA
#undef GAT_WGEN

    // ---- partial denominators: reduce over the 8 producer threads per row
    dsum += __shfl_xor(dsum, 1);
    dsum += __shfl_xor(dsum, 2);
    dsum += __shfl_xor(dsum, 4);
    if (jg == 0) denomp[(size_t)js * NR + r0 + prow] = dsum;

    // ---- partial numerators
    float* np = nump + (size_t)js * NR * FD;
#pragma unroll
    for (int i = 0; i < 4; ++i)
#pragma unroll
        for (int nt = 0; nt < 4; ++nt)
#pragma unroll
            for (int r = 0; r < 4; ++r) {
                int row = r0 + i * 16 + q * 4 + r;
                int col = w * 64 + nt * 16 + m;
                np[(size_t)row * FD + col] = acc[i][nt][r];
            }
}

// ---------------- K5: combine j-split partials, softmax divide, ELU --------
__global__ void k_combine(const float* __restrict__ nump,
                          const float* __restrict__ denomp,
                          float* __restrict__ out)
{
    size_t e = ((size_t)blockIdx.x * 256 + threadIdx.x) * 4;
    int row = (int)(e >> 9);
    float4 n0 = *(const float4*)(nump + e);
    float4 n1 = *(const float4*)(nump + (size_t)NR * FD + e);
    float4 n2 = *(const float4*)(nump + (size_t)2 * NR * FD + e);
    float4 n3 = *(const float4*)(nump + (size_t)3 * NR * FD + e);
    float d = denomp[row] + denomp[NR + row] + denomp[2 * NR + row] + denomp[3 * NR + row];
    float inv = 1.0f / d;
    float4 o;
    o.x = (n0.x + n1.x + n2.x + n3.x) * inv;
    o.y = (n0.y + n1.y + n2.y + n3.y) * inv;
    o.z = (n0.z + n1.z + n2.z + n3.z) * inv;
    o.w = (n0.w + n1.w + n2.w + n3.w) * inv;
    o.x = (o.x > 0.f) ? o.x : (__expf(o.x) - 1.f);
    o.y = (o.y > 0.f) ? o.y : (__expf(o.y) - 1.f);
    o.z = (o.z > 0.f) ? o.z : (__expf(o.z) - 1.f);
    o.w = (o.w > 0.f) ? o.w : (__expf(o.w) - 1.f);
    *(float4*)(out + e) = o;
}

extern "C" void kernel_launch(void* const* d_in, const int* in_sizes, int n_in,
                              void* d_out, int out_size, void* d_ws, size_t ws_size,
                              hipStream_t stream) {
    const float* inp = (const float*)d_in[0];
    const int*   adj = (const int*)d_in[1];
    const float* W1  = (const float*)d_in[2];
    const float* b1  = (const float*)d_in[3];
    const float* a1  = (const float*)d_in[4];
    const float* a2  = (const float*)d_in[5];
    const float* b2  = (const float*)d_in[6];
    float* out = (float*)d_out;

    // workspace layout
    short*    inp_bf = (short*)d_ws;                         // 8 MB
    short*    w1t    = inp_bf + (size_t)NR * FD;             // 0.5 MB
    short*    h      = w1t + (size_t)FD * FD;                // 8 MB
    short*    ht36   = h + (size_t)NR * FD;                  // 9 MB (256 tiles x 36 KB)
    uint32_t* bmw    = (uint32_t*)(ht36 + (size_t)256 * 512 * PADC); // 8 MB
    float*    f1     = (float*)(bmw + (size_t)NR * 256);     // 32 KB
    float*    f2s    = f1 + NR;                              // 32 KB
    float*    nump   = f2s + NR;                             // 64 MB
    float*    denomp = nump + (size_t)4 * NR * FD;           // 128 KB

    k_prepack<<<NR, 256, 0, stream>>>(adj, (unsigned long long*)bmw);
    k_convert<<<(NR * FD / 4) / 256, 256, 0, stream>>>(inp, inp_bf);
    k_w1t<<<(FD * FD) / 256, 256, 0, stream>>>(W1, w1t);
    dim3 g1(NR / 32, FD / 128);
    k_gemm_h<<<g1, 256, 0, stream>>>(inp_bf, w1t, b1, h, ht36);
    k_f1f2<<<NR / 4, 256, 0, stream>>>(h, a1, a2, b2, f1, f2s);
    k_attn<<<128 * 4, 512, 0, stream>>>(bmw, ht36, f1, f2s, nump, denomp);
    k_combine<<<(NR * FD / 4) / 256, 256, 0, stream>>>(nump, denomp, out);
}

// Round 10
// 515.834 us; speedup vs baseline: 1.0971x; 1.0194x over previous
//
#include <hip/hip_runtime.h>
#include <hip/hip_bf16.h>
#include <stdint.h>

#define NR 8192
#define FD 512
#define BM 64     // k_attn rows per band

typedef __attribute__((ext_vector_type(8))) short s8v;   // 8 bf16 (4 VGPRs) - MFMA A/B frag
typedef __attribute__((ext_vector_type(4))) float f32x4; // MFMA C/D frag

static __device__ __forceinline__ short bf16_rtne(float x) {
    union { float f; uint32_t u; } v; v.f = x;
    uint32_t r = (v.u + 0x7FFFu + ((v.u >> 16) & 1u)) >> 16;
    return (short)r;
}
static __device__ __forceinline__ float bf16_to_f32(short s) {
    union { uint32_t u; float f; } v; v.u = ((uint32_t)(uint16_t)s) << 16;
    return v.f;
}

// ---------------- K0: adj -> bitmask via ballot ----------------
__global__ void k_prepack(const int* __restrict__ adj,
                          unsigned long long* __restrict__ bm) {
    const int lane = threadIdx.x & 63;
    const int wv   = threadIdx.x >> 6;          // 4 waves/block
    const int gid  = blockIdx.x * 4 + wv;       // 32768 waves
    const int row  = gid >> 2;
    const int seg  = (gid & 3) * 2048;
    const int* p   = adj + (size_t)row * NR + seg + lane;
    unsigned long long* o = bm + (((size_t)row * NR + seg) >> 6);
#pragma unroll
    for (int g = 0; g < 8; ++g) {               // 8 groups of 256 j
        unsigned long long b0 = __ballot(p[g * 256]       != 0);
        unsigned long long b1 = __ballot(p[g * 256 + 64]  != 0);
        unsigned long long b2 = __ballot(p[g * 256 + 128] != 0);
        unsigned long long b3 = __ballot(p[g * 256 + 192] != 0);
        unsigned long long vs = (lane == 0) ? b0 : (lane == 1) ? b1
                              : (lane == 2) ? b2 : b3;
        if (lane < 4) o[g * 4 + lane] = vs;
    }
}

// ---------------- K0a: fp32 -> bf16 convert (inp) ----------------
__global__ void k_convert(const float* __restrict__ in, short* __restrict__ out) {
    int i = blockIdx.x * blockDim.x + threadIdx.x;   // one float4 per thread
    float4 v = ((const float4*)in)[i];
    short4 s;
    s.x = bf16_rtne(v.x); s.y = bf16_rtne(v.y);
    s.z = bf16_rtne(v.z); s.w = bf16_rtne(v.w);
    ((short4*)out)[i] = s;
}

// ---------------- K0b: W1 [k][n] -> W1T bf16 [n][k] ----------------
__global__ void k_w1t(const float* __restrict__ W1, short* __restrict__ W1T) {
    int i = blockIdx.x * 256 + threadIdx.x;  // 512*512
    int k = i & 511, n = i >> 9;
    W1T[(size_t)n * 512 + k] = bf16_rtne(W1[(size_t)k * 512 + n]);
}

// ---------------- K1: h = inp @ W1 + b1 ; writes h AND ht2 ----------------
// ht2 layout: [jt=row/32][col][row%32] bf16 (tile-contiguous for k_attn DMA)
__launch_bounds__(256)
__global__ void k_gemm_h(const short* __restrict__ A,   // inp bf16 [8192][512]
                         const short* __restrict__ BT,  // W1T bf16 [512][512]
                         const float* __restrict__ b1,
                         short* __restrict__ H,         // bf16 [8192][512]
                         short* __restrict__ HT2)       // bf16 [256][512][32]
{
    const int lane = threadIdx.x & 63;
    const int wn   = threadIdx.x >> 6;     // 0..3
    const int m    = lane & 15;
    const int q    = lane >> 4;
    const int r0   = blockIdx.x * 32;
    const int c0   = blockIdx.y * 128 + wn * 32;

    f32x4 acc[2][2] = {};
#pragma unroll 1
    for (int k0 = 0; k0 < 512; k0 += 32) {
        s8v a[2], b[2];
#pragma unroll
        for (int rt = 0; rt < 2; ++rt)
            a[rt] = *(const s8v*)(A + (size_t)(r0 + rt * 16 + m) * 512 + k0 + q * 8);
#pragma unroll
        for (int nt = 0; nt < 2; ++nt)
            b[nt] = *(const s8v*)(BT + (size_t)(c0 + nt * 16 + m) * 512 + k0 + q * 8);
#pragma unroll
        for (int rt = 0; rt < 2; ++rt)
#pragma unroll
            for (int nt = 0; nt < 2; ++nt)
                acc[rt][nt] = __builtin_amdgcn_mfma_f32_16x16x32_bf16(a[rt], b[nt], acc[rt][nt], 0, 0, 0);
    }
    float b1v[2];
#pragma unroll
    for (int nt = 0; nt < 2; ++nt) b1v[nt] = b1[c0 + nt * 16 + m];

#pragma unroll
    for (int rt = 0; rt < 2; ++rt)
#pragma unroll
        for (int nt = 0; nt < 2; ++nt) {
            int col = c0 + nt * 16 + m;
            short4 hp;
#pragma unroll
            for (int r = 0; r < 4; ++r) {
                int row = r0 + rt * 16 + q * 4 + r;
                short hv = bf16_rtne(acc[rt][nt][r] + b1v[nt]);
                H[(size_t)row * 512 + col] = hv;
                ((short*)&hp)[r] = hv;
            }
            *(short4*)(HT2 + (size_t)blockIdx.x * (512 * 32) + (size_t)col * 32 + rt * 16 + q * 4) = hp;
        }
}

// ---------------- K3: f1 = h@a1, f2s = h@a2 + b2 ----------------
__global__ void k_f1f2(const short* __restrict__ H, const float* __restrict__ a1,
                       const float* __restrict__ a2, const float* __restrict__ b2,
                       float* __restrict__ f1, float* __restrict__ f2s)
{
    const int lane = threadIdx.x & 63;
    const int row  = blockIdx.x * 4 + (threadIdx.x >> 6);
    s8v hv = *(const s8v*)(H + (size_t)row * 512 + lane * 8);
    float4 a1l = ((const float4*)(a1 + lane * 8))[0];
    float4 a1h = ((const float4*)(a1 + lane * 8))[1];
    float4 a2l = ((const float4*)(a2 + lane * 8))[0];
    float4 a2h = ((const float4*)(a2 + lane * 8))[1];
    float hf[8];
#pragma unroll
    for (int i = 0; i < 8; ++i) hf[i] = bf16_to_f32(hv[i]);
    float s1 = hf[0] * a1l.x + hf[1] * a1l.y + hf[2] * a1l.z + hf[3] * a1l.w
             + hf[4] * a1h.x + hf[5] * a1h.y + hf[6] * a1h.z + hf[7] * a1h.w;
    float s2 = hf[0] * a2l.x + hf[1] * a2l.y + hf[2] * a2l.z + hf[3] * a2l.w
             + hf[4] * a2h.x + hf[5] * a2h.y + hf[6] * a2h.z + hf[7] * a2h.w;
#pragma unroll
    for (int o = 32; o > 0; o >>= 1) {
        s1 += __shfl_xor(s1, o);
        s2 += __shfl_xor(s2, o);
    }
    if (lane == 0) {
        f1[row]  = s1;
        f2s[row] = s2 + b2[0];
    }
}

// ---------------- K4: fused masked-softmax attention @ h (partials) --------
// grid 256 = 128 bands x 2 j-splits, 512 thr / 8 waves, LDS 128 KB (1/CU).
// Wave w owns cols w*64..+63 and a PRIVATE LDS B-slice dbuf -> B staging is
// per-wave and barrier-free: issue DMA(kt+1), manual s_waitcnt vmcnt(4)
// (waits only the OLDER batch - compiler can't do this; it doesn't track
// global_load_lds->LDS deps), ds_read tile kt, 16 MFMA. Barrier only at
// 256-j chunk boundaries for the shared weight tile handoff (16 total).
__launch_bounds__(512, 2)
__global__ void k_attn(const uint32_t* __restrict__ bm, // [8192][256] bit j
                       const short* __restrict__ HT2,   // [256][512][32]
                       const float* __restrict__ f1,
                       const float* __restrict__ f2s,
                       float* __restrict__ nump,        // [2][8192][512]
                       float* __restrict__ denomp)      // [2][8192]
{
    __shared__ __align__(16) short wt[2][BM * 256];     // 2 x 32 KB (chunk dbuf)
    __shared__ __align__(16) short bbuf[8][2][2048];    // 8 waves x dbuf x 4 KB

    const int t    = threadIdx.x;
    const int lane = t & 63;
    const int w    = t >> 6;          // 0..7 col group (64 cols)
    const int m    = lane & 15;
    const int q    = lane >> 4;

    const int js   = blockIdx.x & 1;
    const int band = blockIdx.x >> 1; // 0..127
    const int r0   = band * BM;
    const int jb0  = js * 4096;
    const int jt0  = js * 128;        // first 32-j tile index

    // weight producer: row prow, 4 units of 8 j (u = jg + 8k) per 256-j chunk
    const int prow = t >> 3;          // 0..63
    const int jg   = t & 7;

    const float f1v = f1[r0 + prow];
    const uint32_t* bmrow = bm + (size_t)(r0 + prow) * 256 + js * 128;
    const float* f2base = f2s + jb0;

    f32x4 acc[4][4] = {};
    float dsum = 0.f;

#define GAT_DMA(KT)                                                            \
    {                                                                          \
        const short* src_ = HT2 + (size_t)(jt0 + (KT)) * (512 * 32) + w * 2048;\
        short* dst_ = &bbuf[w][(KT) & 1][0];                                   \
        _Pragma("unroll")                                                      \
        for (int b_ = 0; b_ < 4; ++b_) {                                       \
            __builtin_amdgcn_global_load_lds(                                  \
                (const __attribute__((address_space(1))) int*)                 \
                    (src_ + b_ * 512 + lane * 8),                              \
                (__attribute__((address_space(3))) int*)(dst_ + b_ * 512),     \
                16, 0, 0);                                                     \
        }                                                                      \
    }

#define GAT_WGEN(CH, P)                                                        \
    {                                                                          \
        uint4 mwa_ = *(const uint4*)(bmrow + (CH) * 8);                        \
        uint4 mwb_ = *(const uint4*)(bmrow + (CH) * 8 + 4);                    \
        uint32_t m8_[8] = {mwa_.x, mwa_.y, mwa_.z, mwa_.w,                     \
                           mwb_.x, mwb_.y, mwb_.z, mwb_.w};                    \
        _Pragma("unroll")                                                      \
        for (int k_ = 0; k_ < 4; ++k_) {                                       \
            const int u_ = jg + 8 * k_;                                        \
            uint32_t byte_ = (m8_[(jg >> 2) + 2 * k_] >> ((jg & 3) * 8)) & 0xFFu; \
            float4 fa_ = *(const float4*)(f2base + (CH) * 256 + u_ * 8);       \
            float4 fb_ = *(const float4*)(f2base + (CH) * 256 + u_ * 8 + 4);   \
            s8v wv_;                                                           \
            const float* ff_ = (const float*)&fa_;                             \
            _Pragma("unroll")                                                  \
            for (int jj = 0; jj < 4; ++jj) {                                   \
                float s_ = f1v + ff_[jj];                                      \
                float e_ = __expf(fmaxf(s_, 0.2f * s_));                       \
                float x_ = ((byte_ >> jj) & 1u) ? e_ : 0.f;                    \
                dsum += x_; wv_[jj] = bf16_rtne(x_);                           \
            }                                                                  \
            const float* fg_ = (const float*)&fb_;                            \
            _Pragma("unroll")                                                  \
            for (int jj = 0; jj < 4; ++jj) {                                   \
                float s_ = f1v + fg_[jj];                                      \
                float e_ = __expf(fmaxf(s_, 0.2f * s_));                       \
                float x_ = ((byte_ >> (4 + jj)) & 1u) ? e_ : 0.f;              \
                dsum += x_; wv_[4 + jj] = bf16_rtne(x_);                       \
            }                                                                  \
            *(s8v*)&wt[P][prow * 256 + ((u_ ^ (prow & 7)) << 3)] = wv_;        \
        }                                                                      \
    }

    // prologue: stage tile 0 + weights chunk 0
    GAT_DMA(0)
    GAT_WGEN(0, 0)
    __syncthreads();

    int kt = 0;
#pragma unroll 1
    for (int ch = 0; ch < 16; ++ch) {
        const int p = ch & 1;
#pragma unroll
        for (int kk = 0; kk < 8; ++kk, ++kt) {
            const int bufc = kt & 1;
            GAT_DMA((kt + 1) & 127)                 // wraps to dummy on last
            __builtin_amdgcn_s_waitcnt(0x0F74);     // vmcnt(4): older batch done
            s8v af[4];
#pragma unroll
            for (int i = 0; i < 4; ++i)
                af[i] = *(const s8v*)&wt[p][(i * 16 + m) * 256
                                            + (((kk * 4 + q) ^ (m & 7)) << 3)];
            const short* bb = &bbuf[w][bufc][0];
#pragma unroll
            for (int nt = 0; nt < 4; ++nt) {
                s8v b = *(const s8v*)&bb[(nt * 16 + m) * 32 + q * 8];
#pragma unroll
                for (int i = 0; i < 4; ++i)
                    acc[i][nt] = __builtin_amdgcn_mfma_f32_16x16x32_bf16(af[i], b, acc[i][nt], 0, 0, 0);
            }
        }
        if (ch < 15) GAT_WGEN(ch + 1, p ^ 1)
        __syncthreads();
    }
#undef GAT_DMA
#undef GAT_WGEN

    // ---- partial denominators: reduce over the 8 producer threads per row
    dsum += __shfl_xor(dsum, 1);
    dsum += __shfl_xor(dsum, 2);
    dsum += __shfl_xor(dsum, 4);
    if (jg == 0) denomp[(size_t)js * NR + r0 + prow] = dsum;

    // ---- partial numerators
    float* np = nump + (size_t)js * NR * FD;
#pragma unroll
    for (int i = 0; i < 4; ++i)
#pragma unroll
        for (int nt = 0; nt < 4; ++nt)
#pragma unroll
            for (int r = 0; r < 4; ++r) {
                int row = r0 + i * 16 + q * 4 + r;
                int col = w * 64 + nt * 16 + m;
                np[(size_t)row * FD + col] = acc[i][nt][r];
            }
}

// ---------------- K5: combine j-split partials, softmax divide, ELU --------
__global__ void k_combine(const float* __restrict__ nump,
                          const float* __restrict__ denomp,
                          float* __restrict__ out)
{
    size_t e = ((size_t)blockIdx.x * 256 + threadIdx.x) * 4;
    int row = (int)(e >> 9);
    float4 n0 = *(const float4*)(nump + e);
    float4 n1 = *(const float4*)(nump + (size_t)NR * FD + e);
    float d = denomp[row] + denomp[NR + row];
    float inv = 1.0f / d;
    float4 o;
    o.x = (n0.x + n1.x) * inv;
    o.y = (n0.y + n1.y) * inv;
    o.z = (n0.z + n1.z) * inv;
    o.w = (n0.w + n1.w) * inv;
    o.x = (o.x > 0.f) ? o.x : (__expf(o.x) - 1.f);
    o.y = (o.y > 0.f) ? o.y : (__expf(o.y) - 1.f);
    o.z = (o.z > 0.f) ? o.z : (__expf(o.z) - 1.f);
    o.w = (o.w > 0.f) ? o.w : (__expf(o.w) - 1.f);
    *(float4*)(out + e) = o;
}

extern "C" void kernel_launch(void* const* d_in, const int* in_sizes, int n_in,
                              void* d_out, int out_size, void* d_ws, size_t ws_size,
                              hipStream_t stream) {
    const float* inp = (const float*)d_in[0];
    const int*   adj = (const int*)d_in[1];
    const float* W1  = (const float*)d_in[2];
    const float* b1  = (const float*)d_in[3];
    const float* a1  = (const float*)d_in[4];
    const float* a2  = (const float*)d_in[5];
    const float* b2  = (const float*)d_in[6];
    float* out = (float*)d_out;

    // workspace layout
    short*    inp_bf = (short*)d_ws;                        // 8 MB
    short*    w1t    = inp_bf + (size_t)NR * FD;            // 0.5 MB
    short*    h      = w1t + (size_t)FD * FD;               // 8 MB
    short*    ht2    = h + (size_t)NR * FD;                 // 8 MB
    uint32_t* bmw    = (uint32_t*)(ht2 + (size_t)FD * NR);  // 8 MB
    float*    f1     = (float*)(bmw + (size_t)NR * 256);    // 32 KB
    float*    f2s    = f1 + NR;                             // 32 KB
    float*    nump   = f2s + NR;                            // 32 MB
    float*    denomp = nump + (size_t)2 * NR * FD;          // 64 KB

    k_prepack<<<NR, 256, 0, stream>>>(adj, (unsigned long long*)bmw);
    k_convert<<<(NR * FD / 4) / 256, 256, 0, stream>>>(inp, inp_bf);
    k_w1t<<<(FD * FD) / 256, 256, 0, stream>>>(W1, w1t);
    dim3 g1(NR / 32, FD / 128);
    k_gemm_h<<<g1, 256, 0, stream>>>(inp_bf, w1t, b1, h, ht2);
    k_f1f2<<<NR / 4, 256, 0, stream>>>(h, a1, a2, b2, f1, f2s);
    k_attn<<<128 * 2, 512, 0, stream>>>(bmw, ht2, f1, f2s, nump, denomp);
    k_combine<<<(NR * FD / 4) / 256, 256, 0, stream>>>(nump, denomp, out);
}

// Round 11
// 513.552 us; speedup vs baseline: 1.1020x; 1.0044x over previous
//
#include <hip/hip_runtime.h>
#include <hip/hip_bf16.h>
#include <stdint.h>

#define NR 8192
#define FD 512
#define BM 64     // k_attn rows per band

typedef __attribute__((ext_vector_type(8))) short s8v;   // 8 bf16 (4 VGPRs) - MFMA A/B frag
typedef __attribute__((ext_vector_type(4))) float f32x4; // MFMA C/D frag

static __device__ __forceinline__ short bf16_rtne(float x) {
    union { float f; uint32_t u; } v; v.f = x;
    uint32_t r = (v.u + 0x7FFFu + ((v.u >> 16) & 1u)) >> 16;
    return (short)r;
}
static __device__ __forceinline__ float bf16_to_f32(short s) {
    union { uint32_t u; float f; } v; v.u = ((uint32_t)(uint16_t)s) << 16;
    return v.f;
}

// ---------------- K0: adj -> bitmask via ballot ----------------
__global__ void k_prepack(const int* __restrict__ adj,
                          unsigned long long* __restrict__ bm) {
    const int lane = threadIdx.x & 63;
    const int wv   = threadIdx.x >> 6;          // 4 waves/block
    const int gid  = blockIdx.x * 4 + wv;       // 32768 waves
    const int row  = gid >> 2;
    const int seg  = (gid & 3) * 2048;
    const int* p   = adj + (size_t)row * NR + seg + lane;
    unsigned long long* o = bm + (((size_t)row * NR + seg) >> 6);
#pragma unroll
    for (int g = 0; g < 8; ++g) {               // 8 groups of 256 j
        unsigned long long b0 = __ballot(p[g * 256]       != 0);
        unsigned long long b1 = __ballot(p[g * 256 + 64]  != 0);
        unsigned long long b2 = __ballot(p[g * 256 + 128] != 0);
        unsigned long long b3 = __ballot(p[g * 256 + 192] != 0);
        unsigned long long vs = (lane == 0) ? b0 : (lane == 1) ? b1
                              : (lane == 2) ? b2 : b3;
        if (lane < 4) o[g * 4 + lane] = vs;
    }
}

// ---------------- K0a: fp32 -> bf16 convert (inp) ----------------
__global__ void k_convert(const float* __restrict__ in, short* __restrict__ out) {
    int i = blockIdx.x * blockDim.x + threadIdx.x;   // one float4 per thread
    float4 v = ((const float4*)in)[i];
    short4 s;
    s.x = bf16_rtne(v.x); s.y = bf16_rtne(v.y);
    s.z = bf16_rtne(v.z); s.w = bf16_rtne(v.w);
    ((short4*)out)[i] = s;
}

// ---------------- K0b: W1 [k][n] -> W1T bf16 [n][k] ----------------
__global__ void k_w1t(const float* __restrict__ W1, short* __restrict__ W1T) {
    int i = blockIdx.x * 256 + threadIdx.x;  // 512*512
    int k = i & 511, n = i >> 9;
    W1T[(size_t)n * 512 + k] = bf16_rtne(W1[(size_t)k * 512 + n]);
}

// ---------------- K1: h = inp @ W1 + b1 ; writes h AND ht3 ----------------
// ht3 layout per 32-j tile jt: [wave=c/64][nt=(c%64)/16][qg=jrow/8][cm=c%16][jr=jrow%8]
// With the DMA's forced lane-linear LDS image, every k_attn b-read instruction
// then reads a contiguous lane-linear 1KB block -> LDS bank-conflict-free.
__launch_bounds__(256)
__global__ void k_gemm_h(const short* __restrict__ A,   // inp bf16 [8192][512]
                         const short* __restrict__ BT,  // W1T bf16 [512][512]
                         const float* __restrict__ b1,
                         short* __restrict__ H,         // bf16 [8192][512]
                         short* __restrict__ HT3)       // bf16 [256][16384]
{
    const int lane = threadIdx.x & 63;
    const int wn   = threadIdx.x >> 6;     // 0..3
    const int m    = lane & 15;
    const int q    = lane >> 4;
    const int r0   = blockIdx.x * 32;
    const int c0   = blockIdx.y * 128 + wn * 32;

    f32x4 acc[2][2] = {};
#pragma unroll 1
    for (int k0 = 0; k0 < 512; k0 += 32) {
        s8v a[2], b[2];
#pragma unroll
        for (int rt = 0; rt < 2; ++rt)
            a[rt] = *(const s8v*)(A + (size_t)(r0 + rt * 16 + m) * 512 + k0 + q * 8);
#pragma unroll
        for (int nt = 0; nt < 2; ++nt)
            b[nt] = *(const s8v*)(BT + (size_t)(c0 + nt * 16 + m) * 512 + k0 + q * 8);
#pragma unroll
        for (int rt = 0; rt < 2; ++rt)
#pragma unroll
            for (int nt = 0; nt < 2; ++nt)
                acc[rt][nt] = __builtin_amdgcn_mfma_f32_16x16x32_bf16(a[rt], b[nt], acc[rt][nt], 0, 0, 0);
    }
    float b1v[2];
#pragma unroll
    for (int nt = 0; nt < 2; ++nt) b1v[nt] = b1[c0 + nt * 16 + m];

#pragma unroll
    for (int rt = 0; rt < 2; ++rt)
#pragma unroll
        for (int nt = 0; nt < 2; ++nt) {
            int col = c0 + nt * 16 + m;
            short4 hp;
#pragma unroll
            for (int r = 0; r < 4; ++r) {
                int row = r0 + rt * 16 + q * 4 + r;
                short hv = bf16_rtne(acc[rt][nt][r] + b1v[nt]);
                H[(size_t)row * 512 + col] = hv;
                ((short*)&hp)[r] = hv;
            }
            // ht3: tile jt = blockIdx.x (rows r0..r0+31)
            // c>>6 = by*2 + (wn>>1); (c>>4)&3 = (wn*2+nt)&3; cm = m
            // qg = rt*2 + (q>>1); jr base = (q&1)*4
            size_t off = (size_t)blockIdx.x * 16384
                       + (size_t)(blockIdx.y * 2 + (wn >> 1)) * 2048
                       + (size_t)((wn * 2 + nt) & 3) * 512
                       + (rt * 2 + (q >> 1)) * 128
                       + m * 8 + (q & 1) * 4;
            *(short4*)(HT3 + off) = hp;
        }
}

// ---------------- K3: f1 = h@a1, f2s = h@a2 + b2 ----------------
__global__ void k_f1f2(const short* __restrict__ H, const float* __restrict__ a1,
                       const float* __restrict__ a2, const float* __restrict__ b2,
                       float* __restrict__ f1, float* __restrict__ f2s)
{
    const int lane = threadIdx.x & 63;
    const int row  = blockIdx.x * 4 + (threadIdx.x >> 6);
    s8v hv = *(const s8v*)(H + (size_t)row * 512 + lane * 8);
    float4 a1l = ((const float4*)(a1 + lane * 8))[0];
    float4 a1h = ((const float4*)(a1 + lane * 8))[1];
    float4 a2l = ((const float4*)(a2 + lane * 8))[0];
    float4 a2h = ((const float4*)(a2 + lane * 8))[1];
    float hf[8];
#pragma unroll
    for (int i = 0; i < 8; ++i) hf[i] = bf16_to_f32(hv[i]);
    float s1 = hf[0] * a1l.x + hf[1] * a1l.y + hf[2] * a1l.z + hf[3] * a1l.w
             + hf[4] * a1h.x + hf[5] * a1h.y + hf[6] * a1h.z + hf[7] * a1h.w;
    float s2 = hf[0] * a2l.x + hf[1] * a2l.y + hf[2] * a2l.z + hf[3] * a2l.w
             + hf[4] * a2h.x + hf[5] * a2h.y + hf[6] * a2h.z + hf[7] * a2h.w;
#pragma unroll
    for (int o = 32; o > 0; o >>= 1) {
        s1 += __shfl_xor(s1, o);
        s2 += __shfl_xor(s2, o);
    }
    if (lane == 0) {
        f1[row]  = s1;
        f2s[row] = s2 + b2[0];
    }
}

// ---------------- K4: fused masked-softmax attention @ h (partials) --------
// grid 256 = 128 bands x 2 j-splits, 512 thr / 8 waves, LDS 128 KB (1/CU).
// Per-wave private B dbuf staged by global_load_lds (no VGPR cost); manual
// s_waitcnt vmcnt(4) waits only the OLDER DMA batch (AITER pattern). B-reads
// are lane-linear contiguous (ht3 layout) -> bank-conflict-free. Barrier only
// at 256-j chunk boundaries for the shared weight-tile handoff (16 total).
__launch_bounds__(512, 2)
__global__ void k_attn(const uint32_t* __restrict__ bm, // [8192][256] bit j
                       const short* __restrict__ HT3,   // [256][16384]
                       const float* __restrict__ f1,
                       const float* __restrict__ f2s,
                       float* __restrict__ nump,        // [2][8192][512]
                       float* __restrict__ denomp)      // [2][8192]
{
    __shared__ __align__(16) short wt[2][BM * 256];     // 2 x 32 KB (chunk dbuf)
    __shared__ __align__(16) short bbuf[8][2][2048];    // 8 waves x dbuf x 4 KB

    const int t    = threadIdx.x;
    const int lane = t & 63;
    const int w    = t >> 6;          // 0..7 col group (64 cols)
    const int m    = lane & 15;
    const int q    = lane >> 4;

    const int js   = blockIdx.x & 1;
    const int band = blockIdx.x >> 1; // 0..127
    const int r0   = band * BM;
    const int jb0  = js * 4096;
    const int jt0  = js * 128;        // first 32-j tile index

    // weight producer: row prow, 4 units of 8 j (u = jg + 8k) per 256-j chunk
    const int prow = t >> 3;          // 0..63
    const int jg   = t & 7;

    const float f1v = f1[r0 + prow];
    const uint32_t* bmrow = bm + (size_t)(r0 + prow) * 256 + js * 128;
    const float* f2base = f2s + jb0;

    f32x4 acc[4][4] = {};
    float dsum = 0.f;

#define GAT_DMA(KT)                                                            \
    {                                                                          \
        const short* src_ = HT3 + (size_t)(jt0 + (KT)) * 16384 + w * 2048;     \
        short* dst_ = &bbuf[w][(KT) & 1][0];                                   \
        _Pragma("unroll")                                                      \
        for (int b_ = 0; b_ < 4; ++b_) {                                       \
            __builtin_amdgcn_global_load_lds(                                  \
                (const __attribute__((address_space(1))) int*)                 \
                    (src_ + b_ * 512 + lane * 8),                              \
                (__attribute__((address_space(3))) int*)(dst_ + b_ * 512),     \
                16, 0, 0);                                                     \
        }                                                                      \
    }

#define GAT_WGEN(CH, P)                                                        \
    {                                                                          \
        uint4 mwa_ = *(const uint4*)(bmrow + (CH) * 8);                        \
        uint4 mwb_ = *(const uint4*)(bmrow + (CH) * 8 + 4);                    \
        uint32_t m8_[8] = {mwa_.x, mwa_.y, mwa_.z, mwa_.w,                     \
                           mwb_.x, mwb_.y, mwb_.z, mwb_.w};                    \
        _Pragma("unroll")                                                      \
        for (int k_ = 0; k_ < 4; ++k_) {                                       \
            const int u_ = jg + 8 * k_;                                        \
            uint32_t byte_ = (m8_[(jg >> 2) + 2 * k_] >> ((jg & 3) * 8)) & 0xFFu; \
            float4 fa_ = *(const float4*)(f2base + (CH) * 256 + u_ * 8);       \
            float4 fb_ = *(const float4*)(f2base + (CH) * 256 + u_ * 8 + 4);   \
            s8v wv_;                                                           \
            const float* ff_ = (const float*)&fa_;                             \
            _Pragma("unroll")                                                  \
            for (int jj = 0; jj < 4; ++jj) {                                   \
                float s_ = f1v + ff_[jj];                                      \
                float e_ = __expf(fmaxf(s_, 0.2f * s_));                       \
                float x_ = ((byte_ >> jj) & 1u) ? e_ : 0.f;                    \
                dsum += x_; wv_[jj] = bf16_rtne(x_);                           \
            }                                                                  \
            const float* fg_ = (const float*)&fb_;                            \
            _Pragma("unroll")                                                  \
            for (int jj = 0; jj < 4; ++jj) {                                   \
                float s_ = f1v + fg_[jj];                                      \
                float e_ = __expf(fmaxf(s_, 0.2f * s_));                       \
                float x_ = ((byte_ >> (4 + jj)) & 1u) ? e_ : 0.f;              \
                dsum += x_; wv_[4 + jj] = bf16_rtne(x_);                       \
            }                                                                  \
            *(s8v*)&wt[P][prow * 256 + ((u_ ^ (prow & 7)) << 3)] = wv_;        \
        }                                                                      \
    }

    // prologue: stage tile 0 + weights chunk 0
    GAT_DMA(0)
    GAT_WGEN(0, 0)
    __syncthreads();

    int kt = 0;
#pragma unroll 1
    for (int ch = 0; ch < 16; ++ch) {
        const int p = ch & 1;
#pragma unroll
        for (int kk = 0; kk < 8; ++kk, ++kt) {
            const int bufc = kt & 1;
            GAT_DMA((kt + 1) & 127)                 // wraps to dummy on last
            __builtin_amdgcn_s_waitcnt(0x0F74);     // vmcnt(4): older batch done
            s8v af[4];
#pragma unroll
            for (int i = 0; i < 4; ++i)
                af[i] = *(const s8v*)&wt[p][(i * 16 + m) * 256
                                            + (((kk * 4 + q) ^ (m & 7)) << 3)];
            const short* bb = &bbuf[w][bufc][0];
#pragma unroll
            for (int nt = 0; nt < 4; ++nt) {
                // lane-linear: byte addr = nt*1024 + lane*16 -> conflict-free
                s8v b = *(const s8v*)&bb[nt * 512 + q * 128 + m * 8];
#pragma unroll
                for (int i = 0; i < 4; ++i)
                    acc[i][nt] = __builtin_amdgcn_mfma_f32_16x16x32_bf16(af[i], b, acc[i][nt], 0, 0, 0);
            }
        }
        if (ch < 15) GAT_WGEN(ch + 1, p ^ 1)
        __syncthreads();
    }
#undef GAT_DMA
#undef GAT_WGEN

    // ---- partial denominators: reduce over the 8 producer threads per row
    dsum += __shfl_xor(dsum, 1);
    dsum += __shfl_xor(dsum, 2);
    dsum += __shfl_xor(dsum, 4);
    if (jg == 0) denomp[(size_t)js * NR + r0 + prow] = dsum;

    // ---- partial numerators
    float* np = nump + (size_t)js * NR * FD;
#pragma unroll
    for (int i = 0; i < 4; ++i)
#pragma unroll
        for (int nt = 0; nt < 4; ++nt)
#pragma unroll
            for (int r = 0; r < 4; ++r) {
                int row = r0 + i * 16 + q * 4 + r;
                int col = w * 64 + nt * 16 + m;
                np[(size_t)row * FD + col] = acc[i][nt][r];
            }
}

// ---------------- K5: combine j-split partials, softmax divide, ELU --------
__global__ void k_combine(const float* __restrict__ nump,
                          const float* __restrict__ denomp,
                          float* __restrict__ out)
{
    size_t e = ((size_t)blockIdx.x * 256 + threadIdx.x) * 4;
    int row = (int)(e >> 9);
    float4 n0 = *(const float4*)(nump + e);
    float4 n1 = *(const float4*)(nump + (size_t)NR * FD + e);
    float d = denomp[row] + denomp[NR + row];
    float inv = 1.0f / d;
    float4 o;
    o.x = (n0.x + n1.x) * inv;
    o.y = (n0.y + n1.y) * inv;
    o.z = (n0.z + n1.z) * inv;
    o.w = (n0.w + n1.w) * inv;
    o.x = (o.x > 0.f) ? o.x : (__expf(o.x) - 1.f);
    o.y = (o.y > 0.f) ? o.y : (__expf(o.y) - 1.f);
    o.z = (o.z > 0.f) ? o.z : (__expf(o.z) - 1.f);
    o.w = (o.w > 0.f) ? o.w : (__expf(o.w) - 1.f);
    *(float4*)(out + e) = o;
}

extern "C" void kernel_launch(void* const* d_in, const int* in_sizes, int n_in,
                              void* d_out, int out_size, void* d_ws, size_t ws_size,
                              hipStream_t stream) {
    const float* inp = (const float*)d_in[0];
    const int*   adj = (const int*)d_in[1];
    const float* W1  = (const float*)d_in[2];
    const float* b1  = (const float*)d_in[3];
    const float* a1  = (const float*)d_in[4];
    const float* a2  = (const float*)d_in[5];
    const float* b2  = (const float*)d_in[6];
    float* out = (float*)d_out;

    // workspace layout
    short*    inp_bf = (short*)d_ws;                        // 8 MB
    short*    w1t    = inp_bf + (size_t)NR * FD;            // 0.5 MB
    short*    h      = w1t + (size_t)FD * FD;               // 8 MB
    short*    ht3    = h + (size_t)NR * FD;                 // 8 MB
    uint32_t* bmw    = (uint32_t*)(ht3 + (size_t)FD * NR);  // 8 MB
    float*    f1     = (float*)(bmw + (size_t)NR * 256);    // 32 KB
    float*    f2s    = f1 + NR;                             // 32 KB
    float*    nump   = f2s + NR;                            // 32 MB
    float*    denomp = nump + (size_t)2 * NR * FD;          // 64 KB

    k_prepack<<<NR, 256, 0, stream>>>(adj, (unsigned long long*)bmw);
    k_convert<<<(NR * FD / 4) / 256, 256, 0, stream>>>(inp, inp_bf);
    k_w1t<<<(FD * FD) / 256, 256, 0, stream>>>(W1, w1t);
    dim3 g1(NR / 32, FD / 128);
    k_gemm_h<<<g1, 256, 0, stream>>>(inp_bf, w1t, b1, h, ht3);
    k_f1f2<<<NR / 4, 256, 0, stream>>>(h, a1, a2, b2, f1, f2s);
    k_attn<<<128 * 2, 512, 0, stream>>>(bmw, ht3, f1, f2s, nump, denomp);
    k_combine<<<(NR * FD / 4) / 256, 256, 0, stream>>>(nump, denomp, out);
}

// Round 12
// 504.987 us; speedup vs baseline: 1.1206x; 1.0170x over previous
//
#include <hip/hip_runtime.h>
#include <hip/hip_bf16.h>
#include <stdint.h>

#define NR 8192
#define FD 512
#define BM 64     // k_attn rows per band

typedef __attribute__((ext_vector_type(8))) short s8v;   // 8 bf16 (4 VGPRs) - MFMA A/B frag
typedef __attribute__((ext_vector_type(4))) float f32x4; // MFMA C/D frag

static __device__ __forceinline__ short bf16_rtne(float x) {
    union { float f; uint32_t u; } v; v.f = x;
    uint32_t r = (v.u + 0x7FFFu + ((v.u >> 16) & 1u)) >> 16;
    return (short)r;
}
static __device__ __forceinline__ float bf16_to_f32(short s) {
    union { uint32_t u; float f; } v; v.u = ((uint32_t)(uint16_t)s) << 16;
    return v.f;
}

// ---------------- K0: adj -> bitmask via ballot ----------------
__global__ void k_prepack(const int* __restrict__ adj,
                          unsigned long long* __restrict__ bm) {
    const int lane = threadIdx.x & 63;
    const int wv   = threadIdx.x >> 6;          // 4 waves/block
    const int gid  = blockIdx.x * 4 + wv;       // 32768 waves
    const int row  = gid >> 2;
    const int seg  = (gid & 3) * 2048;
    const int* p   = adj + (size_t)row * NR + seg + lane;
    unsigned long long* o = bm + (((size_t)row * NR + seg) >> 6);
#pragma unroll
    for (int g = 0; g < 8; ++g) {               // 8 groups of 256 j
        unsigned long long b0 = __ballot(p[g * 256]       != 0);
        unsigned long long b1 = __ballot(p[g * 256 + 64]  != 0);
        unsigned long long b2 = __ballot(p[g * 256 + 128] != 0);
        unsigned long long b3 = __ballot(p[g * 256 + 192] != 0);
        unsigned long long vs = (lane == 0) ? b0 : (lane == 1) ? b1
                              : (lane == 2) ? b2 : b3;
        if (lane < 4) o[g * 4 + lane] = vs;
    }
}

// ---------------- K0a: fp32 -> bf16 convert (inp) ----------------
__global__ void k_convert(const float* __restrict__ in, short* __restrict__ out) {
    int i = blockIdx.x * blockDim.x + threadIdx.x;   // one float4 per thread
    float4 v = ((const float4*)in)[i];
    short4 s;
    s.x = bf16_rtne(v.x); s.y = bf16_rtne(v.y);
    s.z = bf16_rtne(v.z); s.w = bf16_rtne(v.w);
    ((short4*)out)[i] = s;
}

// ---------------- K0b: W1 [k][n] -> W1T bf16 [n][k] ----------------
__global__ void k_w1t(const float* __restrict__ W1, short* __restrict__ W1T) {
    int i = blockIdx.x * 256 + threadIdx.x;  // 512*512
    int k = i & 511, n = i >> 9;
    W1T[(size_t)n * 512 + k] = bf16_rtne(W1[(size_t)k * 512 + n]);
}

// ---------------- K1: h = inp @ W1 + b1 ; writes h AND ht3 ----------------
// ht3 layout per 32-j tile jt: [wave=c/64][nt=(c%64)/16][qg=jrow/8][cm=c%16][jr=jrow%8]
// -> every k_attn B-frag load is a fully-coalesced lane-linear 1KB dwordx4.
__launch_bounds__(256)
__global__ void k_gemm_h(const short* __restrict__ A,   // inp bf16 [8192][512]
                         const short* __restrict__ BT,  // W1T bf16 [512][512]
                         const float* __restrict__ b1,
                         short* __restrict__ H,         // bf16 [8192][512]
                         short* __restrict__ HT3)       // bf16 [256][16384]
{
    const int lane = threadIdx.x & 63;
    const int wn   = threadIdx.x >> 6;     // 0..3
    const int m    = lane & 15;
    const int q    = lane >> 4;
    const int r0   = blockIdx.x * 32;
    const int c0   = blockIdx.y * 128 + wn * 32;

    f32x4 acc[2][2] = {};
#pragma unroll 1
    for (int k0 = 0; k0 < 512; k0 += 32) {
        s8v a[2], b[2];
#pragma unroll
        for (int rt = 0; rt < 2; ++rt)
            a[rt] = *(const s8v*)(A + (size_t)(r0 + rt * 16 + m) * 512 + k0 + q * 8);
#pragma unroll
        for (int nt = 0; nt < 2; ++nt)
            b[nt] = *(const s8v*)(BT + (size_t)(c0 + nt * 16 + m) * 512 + k0 + q * 8);
#pragma unroll
        for (int rt = 0; rt < 2; ++rt)
#pragma unroll
            for (int nt = 0; nt < 2; ++nt)
                acc[rt][nt] = __builtin_amdgcn_mfma_f32_16x16x32_bf16(a[rt], b[nt], acc[rt][nt], 0, 0, 0);
    }
    float b1v[2];
#pragma unroll
    for (int nt = 0; nt < 2; ++nt) b1v[nt] = b1[c0 + nt * 16 + m];

#pragma unroll
    for (int rt = 0; rt < 2; ++rt)
#pragma unroll
        for (int nt = 0; nt < 2; ++nt) {
            int col = c0 + nt * 16 + m;
            short4 hp;
#pragma unroll
            for (int r = 0; r < 4; ++r) {
                int row = r0 + rt * 16 + q * 4 + r;
                short hv = bf16_rtne(acc[rt][nt][r] + b1v[nt]);
                H[(size_t)row * 512 + col] = hv;
                ((short*)&hp)[r] = hv;
            }
            size_t off = (size_t)blockIdx.x * 16384
                       + (size_t)(blockIdx.y * 2 + (wn >> 1)) * 2048
                       + (size_t)((wn * 2 + nt) & 3) * 512
                       + (rt * 2 + (q >> 1)) * 128
                       + m * 8 + (q & 1) * 4;
            *(short4*)(HT3 + off) = hp;
        }
}

// ---------------- K3: f1 = h@a1, f2s = h@a2 + b2 ----------------
__global__ void k_f1f2(const short* __restrict__ H, const float* __restrict__ a1,
                       const float* __restrict__ a2, const float* __restrict__ b2,
                       float* __restrict__ f1, float* __restrict__ f2s)
{
    const int lane = threadIdx.x & 63;
    const int row  = blockIdx.x * 4 + (threadIdx.x >> 6);
    s8v hv = *(const s8v*)(H + (size_t)row * 512 + lane * 8);
    float4 a1l = ((const float4*)(a1 + lane * 8))[0];
    float4 a1h = ((const float4*)(a1 + lane * 8))[1];
    float4 a2l = ((const float4*)(a2 + lane * 8))[0];
    float4 a2h = ((const float4*)(a2 + lane * 8))[1];
    float hf[8];
#pragma unroll
    for (int i = 0; i < 8; ++i) hf[i] = bf16_to_f32(hv[i]);
    float s1 = hf[0] * a1l.x + hf[1] * a1l.y + hf[2] * a1l.z + hf[3] * a1l.w
             + hf[4] * a1h.x + hf[5] * a1h.y + hf[6] * a1h.z + hf[7] * a1h.w;
    float s2 = hf[0] * a2l.x + hf[1] * a2l.y + hf[2] * a2l.z + hf[3] * a2l.w
             + hf[4] * a2h.x + hf[5] * a2h.y + hf[6] * a2h.z + hf[7] * a2h.w;
#pragma unroll
    for (int o = 32; o > 0; o >>= 1) {
        s1 += __shfl_xor(s1, o);
        s2 += __shfl_xor(s2, o);
    }
    if (lane == 0) {
        f1[row]  = s1;
        f2s[row] = s2 + b2[0];
    }
}

// ---------------- K4: fused masked-softmax attention @ h (partials) --------
// grid 256 = 128 bands x 2 j-splits, 512 thr / 8 waves.
// B-frags: depth-2 REGISTER prefetch from ht3 (coalesced 1KB dwordx4; compiler
// emits precise per-register vmcnt waits). Weight tile: LDS dbuf (64 KB only),
// with WGEN split into per-kt unit pieces issued in the MFMA shadow (kk=2..5)
// and chunk inputs loaded at kk=0 (2 kt of latency distance). One barrier per
// 256-j chunk (16 total) solely for the wt handoff.
__launch_bounds__(512, 2)
__global__ void k_attn(const uint32_t* __restrict__ bm, // [8192][256] bit j
                       const short* __restrict__ HT3,   // [256][16384]
                       const float* __restrict__ f1,
                       const float* __restrict__ f2s,
                       float* __restrict__ nump,        // [2][8192][512]
                       float* __restrict__ denomp)      // [2][8192]
{
    __shared__ __align__(16) short wt[2][BM * 256];     // 2 x 32 KB

    const int t    = threadIdx.x;
    const int lane = t & 63;
    const int w    = t >> 6;          // 0..7 col group (64 cols)
    const int m    = lane & 15;
    const int q    = lane >> 4;

    const int js   = blockIdx.x & 1;
    const int band = blockIdx.x >> 1; // 0..127
    const int r0   = band * BM;
    const int jb0  = js * 4096;
    const int jt0  = js * 128;        // first 32-j tile index

    const int prow = t >> 3;          // 0..63
    const int jg   = t & 7;

    const float f1v = f1[r0 + prow];
    const uint32_t* bmrow = bm + (size_t)(r0 + prow) * 256 + js * 128;
    const float* f2base = f2s + jb0;

    f32x4 acc[4][4] = {};
    float dsum = 0.f;

#define GAT_BLOAD(DST, KT)                                                     \
    {                                                                          \
        const short* s_ = HT3 + (size_t)(jt0 + (KT)) * 16384 + w * 2048        \
                        + q * 128 + m * 8;                                     \
        DST[0] = *(const s8v*)(s_);                                            \
        DST[1] = *(const s8v*)(s_ + 512);                                      \
        DST[2] = *(const s8v*)(s_ + 1024);                                     \
        DST[3] = *(const s8v*)(s_ + 1536);                                     \
    }

// one unit (8 weights) of row prow into wt[P]; BYTE = 8-bit mask, FA/FB float4
#define GAT_WUNIT(U, BYTE, FA, FB, P)                                          \
    {                                                                          \
        s8v wv_;                                                               \
        const float* ff_ = (const float*)&(FA);                                \
        _Pragma("unroll")                                                      \
        for (int jj = 0; jj < 4; ++jj) {                                       \
            float s_ = f1v + ff_[jj];                                          \
            float e_ = __expf(fmaxf(s_, 0.2f * s_));                           \
            float x_ = (((BYTE) >> jj) & 1u) ? e_ : 0.f;                       \
            dsum += x_; wv_[jj] = bf16_rtne(x_);                               \
        }                                                                      \
        const float* fg_ = (const float*)&(FB);                               \
        _Pragma("unroll")                                                      \
        for (int jj = 0; jj < 4; ++jj) {                                       \
            float s_ = f1v + fg_[jj];                                          \
            float e_ = __expf(fmaxf(s_, 0.2f * s_));                           \
            float x_ = (((BYTE) >> (4 + jj)) & 1u) ? e_ : 0.f;                 \
            dsum += x_; wv_[4 + jj] = bf16_rtne(x_);                           \
        }                                                                      \
        *(s8v*)&wt[P][prow * 256 + (((U) ^ (prow & 7)) << 3)] = wv_;           \
    }

    // prologue: full WGEN for chunk 0 -> wt[0]; preload B tiles 0 and 1
    {
        uint4 mwa_ = *(const uint4*)(bmrow);
        uint4 mwb_ = *(const uint4*)(bmrow + 4);
        uint32_t m8_[8] = {mwa_.x, mwa_.y, mwa_.z, mwa_.w,
                           mwb_.x, mwb_.y, mwb_.z, mwb_.w};
#pragma unroll
        for (int k_ = 0; k_ < 4; ++k_) {
            const int u_ = jg + 8 * k_;
            uint32_t byte_ = (m8_[(jg >> 2) + 2 * k_] >> ((jg & 3) * 8)) & 0xFFu;
            float4 fa_ = *(const float4*)(f2base + u_ * 8);
            float4 fb_ = *(const float4*)(f2base + u_ * 8 + 4);
            GAT_WUNIT(u_, byte_, fa_, fb_, 0)
        }
    }
    s8v breg[2][4];
    GAT_BLOAD(breg[0], 0)
    GAT_BLOAD(breg[1], 1)
    __syncthreads();

    int kt = 0;
#pragma unroll 1
    for (int ch = 0; ch < 16; ++ch) {
        const int p = ch & 1;
        // inputs for chunk ch+1's weight pieces (used from kk=2 -> 2-kt distance)
        const int chn = (ch + 1) & 15;
        uint4 mwa_ = *(const uint4*)(bmrow + chn * 8);
        uint4 mwb_ = *(const uint4*)(bmrow + chn * 8 + 4);
        float4 fa_[4], fb_[4];
#pragma unroll
        for (int k_ = 0; k_ < 4; ++k_) {
            const int u_ = jg + 8 * k_;
            fa_[k_] = *(const float4*)(f2base + chn * 256 + u_ * 8);
            fb_[k_] = *(const float4*)(f2base + chn * 256 + u_ * 8 + 4);
        }
        uint32_t m8_[8] = {mwa_.x, mwa_.y, mwa_.z, mwa_.w,
                           mwb_.x, mwb_.y, mwb_.z, mwb_.w};

#pragma unroll
        for (int kk = 0; kk < 8; ++kk, ++kt) {
            const int e = kk & 1;                // kt&1 == kk&1 (8 kts/chunk)
            // issue B loads for kt+2 (consumed 2 kts later; wraps to dummy)
            s8v bn[4];
            GAT_BLOAD(bn, (kt + 2) & 127)
            // A-frags from LDS weight tile
            s8v af[4];
#pragma unroll
            for (int i = 0; i < 4; ++i)
                af[i] = *(const s8v*)&wt[p][(i * 16 + m) * 256
                                            + (((kk * 4 + q) ^ (m & 7)) << 3)];
            // 16 MFMAs on current B regs
#pragma unroll
            for (int nt = 0; nt < 4; ++nt)
#pragma unroll
                for (int i = 0; i < 4; ++i)
                    acc[i][nt] = __builtin_amdgcn_mfma_f32_16x16x32_bf16(af[i], breg[e][nt], acc[i][nt], 0, 0, 0);
            // weight piece for next chunk in the MFMA shadow
            if (kk >= 2 && kk <= 5 && ch < 15) {
                const int k_ = kk - 2;
                const int u_ = jg + 8 * k_;
                uint32_t byte_ = (m8_[(jg >> 2) + 2 * k_] >> ((jg & 3) * 8)) & 0xFFu;
                GAT_WUNIT(u_, byte_, fa_[k_], fb_[k_], p ^ 1)
            }
            // rotate B regs
#pragma unroll
            for (int nt = 0; nt < 4; ++nt) breg[e][nt] = bn[nt];
        }
        __syncthreads();
    }
#undef GAT_BLOAD
#undef GAT_WUNIT

    // ---- partial denominators: reduce over the 8 producer threads per row
    dsum += __shfl_xor(dsum, 1);
    dsum += __shfl_xor(dsum, 2);
    dsum += __shfl_xor(dsum, 4);
    if (jg == 0) denomp[(size_t)js * NR + r0 + prow] = dsum;

    // ---- partial numerators
    float* np = nump + (size_t)js * NR * FD;
#pragma unroll
    for (int i = 0; i < 4; ++i)
#pragma unroll
        for (int nt = 0; nt < 4; ++nt)
#pragma unroll
            for (int r = 0; r < 4; ++r) {
                int row = r0 + i * 16 + q * 4 + r;
                int col = w * 64 + nt * 16 + m;
                np[(size_t)row * FD + col] = acc[i][nt][r];
            }
}

// ---------------- K5: combine j-split partials, softmax divide, ELU --------
__global__ void k_combine(const float* __restrict__ nump,
                          const float* __restrict__ denomp,
                          float* __restrict__ out)
{
    size_t e = ((size_t)blockIdx.x * 256 + threadIdx.x) * 4;
    int row = (int)(e >> 9);
    float4 n0 = *(const float4*)(nump + e);
    float4 n1 = *(const float4*)(nump + (size_t)NR * FD + e);
    float d = denomp[row] + denomp[NR + row];
    float inv = 1.0f / d;
    float4 o;
    o.x = (n0.x + n1.x) * inv;
    o.y = (n0.y + n1.y) * inv;
    o.z = (n0.z + n1.z) * inv;
    o.w = (n0.w + n1.w) * inv;
    o.x = (o.x > 0.f) ? o.x : (__expf(o.x) - 1.f);
    o.y = (o.y > 0.f) ? o.y : (__expf(o.y) - 1.f);
    o.z = (o.z > 0.f) ? o.z : (__expf(o.z) - 1.f);
    o.w = (o.w > 0.f) ? o.w : (__expf(o.w) - 1.f);
    *(float4*)(out + e) = o;
}

extern "C" void kernel_launch(void* const* d_in, const int* in_sizes, int n_in,
                              void* d_out, int out_size, void* d_ws, size_t ws_size,
                              hipStream_t stream) {
    const float* inp = (const float*)d_in[0];
    const int*   adj = (const int*)d_in[1];
    const float* W1  = (const float*)d_in[2];
    const float* b1  = (const float*)d_in[3];
    const float* a1  = (const float*)d_in[4];
    const float* a2  = (const float*)d_in[5];
    const float* b2  = (const float*)d_in[6];
    float* out = (float*)d_out;

    // workspace layout
    short*    inp_bf = (short*)d_ws;                        // 8 MB
    short*    w1t    = inp_bf + (size_t)NR * FD;            // 0.5 MB
    short*    h      = w1t + (size_t)FD * FD;               // 8 MB
    short*    ht3    = h + (size_t)NR * FD;                 // 8 MB
    uint32_t* bmw    = (uint32_t*)(ht3 + (size_t)FD * NR);  // 8 MB
    float*    f1     = (float*)(bmw + (size_t)NR * 256);    // 32 KB
    float*    f2s    = f1 + NR;                             // 32 KB
    float*    nump   = f2s + NR;                            // 32 MB
    float*    denomp = nump + (size_t)2 * NR * FD;          // 64 KB

    k_prepack<<<NR, 256, 0, stream>>>(adj, (unsigned long long*)bmw);
    k_convert<<<(NR * FD / 4) / 256, 256, 0, stream>>>(inp, inp_bf);
    k_w1t<<<(FD * FD) / 256, 256, 0, stream>>>(W1, w1t);
    dim3 g1(NR / 32, FD / 128);
    k_gemm_h<<<g1, 256, 0, stream>>>(inp_bf, w1t, b1, h, ht3);
    k_f1f2<<<NR / 4, 256, 0, stream>>>(h, a1, a2, b2, f1, f2s);
    k_attn<<<128 * 2, 512, 0, stream>>>(bmw, ht3, f1, f2s, nump, denomp);
    k_combine<<<(NR * FD / 4) / 256, 256, 0, stream>>>(nump, denomp, out);
}